// Round 4
// baseline (1413.439 us; speedup 1.0000x reference)
//
#include <hip/hip_runtime.h>
#include <hip/hip_bf16.h>

#define NLAYER 4
#define NHEAD 8
#define CEMB 512
#define HS 64
#define VOCAB_N 32000
#define SEQT 2048
#define BATCH_N 2
#define MROWS (BATCH_N * SEQT)   /* 4096 */
#define WIN 64
#define NGLOB 16
#define NRAND 16
#define QB 16                    /* queries per attention block */

typedef __attribute__((ext_vector_type(8))) __bf16 bf16x8;
typedef __attribute__((ext_vector_type(4))) float f32x4;
typedef __attribute__((ext_vector_type(8))) unsigned short u16x8;

__device__ __forceinline__ unsigned short f2bf(float f) {
    unsigned u = __float_as_uint(f);
    u += 0x7fffu + ((u >> 16) & 1u);      // RNE
    return (unsigned short)(u >> 16);
}
__device__ __forceinline__ float bf2f(unsigned short v) {
    return __uint_as_float((unsigned)v << 16);
}

// async global->LDS, 16B per lane, dest = wave-uniform base + lane*16
__device__ __forceinline__ void stage16(const unsigned short* g, unsigned short* l) {
    __builtin_amdgcn_global_load_lds(
        (const __attribute__((address_space(1))) void*)g,
        (__attribute__((address_space(3))) void*)l, 16, 0, 0);
}

// ---------------------------------------------------------------- transposes
__global__ __launch_bounds__(256) void transpose_qkv_kernel(
    const float* __restrict__ Wq, const float* __restrict__ Wk,
    const float* __restrict__ Wv, unsigned short* __restrict__ outT)
{
    __shared__ float t[64][65];
    const int l = blockIdx.z;
    const int sel = blockIdx.y >> 3;
    const int h = blockIdx.y & 7;
    const int c0 = blockIdx.x * 64;
    const float* W = (sel == 0) ? Wq : (sel == 1) ? Wk : Wv;
    const float* in = W + ((size_t)(l * NHEAD + h) * CEMB + c0) * HS;
    const int tid = threadIdx.x;
    #pragma unroll
    for (int i = 0; i < 16; ++i) {
        int idx = tid + i * 256;
        int r = idx >> 6, d = idx & 63;
        t[r][d] = in[r * HS + d];
    }
    __syncthreads();
    unsigned short* out = outT + ((size_t)l * 1536 + sel * 512 + h * 64) * (size_t)CEMB;
    #pragma unroll
    for (int i = 0; i < 16; ++i) {
        int idx = tid + i * 256;
        int d = idx >> 6, r = idx & 63;
        out[(size_t)d * CEMB + c0 + r] = f2bf(t[r][d]);
    }
}

__global__ __launch_bounds__(256) void transpose_mat_kernel(
    const float* __restrict__ in, unsigned short* __restrict__ out, int K, int N)
{
    __shared__ float t[64][65];
    const size_t zo = (size_t)blockIdx.z * K * N;
    const int k0 = blockIdx.x * 64, n0 = blockIdx.y * 64;
    const int tid = threadIdx.x;
    #pragma unroll
    for (int i = 0; i < 16; ++i) {
        int idx = tid + i * 256;
        int r = idx >> 6, c = idx & 63;
        t[r][c] = in[zo + (size_t)(k0 + r) * N + n0 + c];
    }
    __syncthreads();
    #pragma unroll
    for (int i = 0; i < 16; ++i) {
        int idx = tid + i * 256;
        int c = idx >> 6, r = idx & 63;
        out[zo + (size_t)(n0 + c) * K + k0 + r] = f2bf(t[r][c]);
    }
}

// ---------------------------------------------------------------- embedding
__global__ __launch_bounds__(256) void embed_kernel(
    const float* __restrict__ tok_emb, const float* __restrict__ pos_emb,
    const int* __restrict__ toks, float* __restrict__ x)
{
    int i = blockIdx.x * 256 + threadIdx.x;
    int m = i >> 7;
    int c = (i & 127) << 2;
    int tok = toks[m];
    const float4 a = *(const float4*)&tok_emb[(size_t)tok * CEMB + c];
    const float4 p = *(const float4*)&pos_emb[(size_t)(m & (SEQT - 1)) * CEMB + c];
    float4 o;
    o.x = a.x + p.x; o.y = a.y + p.y; o.z = a.z + p.z; o.w = a.w + p.w;
    *(float4*)&x[(size_t)m * CEMB + c] = o;
}

// ---------------------------------------------------------------- layernorm
__global__ __launch_bounds__(256) void ln_kernel(
    const float* __restrict__ x, const float* __restrict__ g,
    const float* __restrict__ b, unsigned short* __restrict__ out)
{
    const int wave = threadIdx.x >> 6, lane = threadIdx.x & 63;
    const int m = blockIdx.x * 4 + wave;
    const float* row = x + (size_t)m * CEMB;
    const float4 v0 = *(const float4*)&row[lane * 8];
    const float4 v1 = *(const float4*)&row[lane * 8 + 4];
    float s  = v0.x + v0.y + v0.z + v0.w + v1.x + v1.y + v1.z + v1.w;
    float s2 = v0.x*v0.x + v0.y*v0.y + v0.z*v0.z + v0.w*v0.w
             + v1.x*v1.x + v1.y*v1.y + v1.z*v1.z + v1.w*v1.w;
    #pragma unroll
    for (int off = 32; off > 0; off >>= 1) {
        s  += __shfl_xor(s, off);
        s2 += __shfl_xor(s2, off);
    }
    const float mu  = s * (1.f / CEMB);
    const float var = s2 * (1.f / CEMB) - mu * mu;
    const float rs  = rsqrtf(var + 1e-5f);
    const float vals[8] = {v0.x, v0.y, v0.z, v0.w, v1.x, v1.y, v1.z, v1.w};
    u16x8 o;
    #pragma unroll
    for (int j = 0; j < 8; ++j)
        o[j] = f2bf((vals[j] - mu) * rs * g[lane * 8 + j] + b[lane * 8 + j]);
    *(u16x8*)&out[(size_t)m * CEMB + lane * 8] = o;
}

// ---------------------------------------------------------------- MFMA GEMM (m97 structure)
// MODE 0: bf16 out, no bias           (qkv)
// MODE 1: f32 out, +bias, +resid      (proj, mlp2)
// MODE 2: bf16 out, +bias, relu       (mlp1)
// MODE 3: f32 out, +bias              (logits)
template<int MODE, bool SWZ>
__global__ __launch_bounds__(256) void gemm_kernel(
    const unsigned short* __restrict__ A, const unsigned short* __restrict__ Bt,
    const float* __restrict__ bias, const float* resid, void* outp,
    int M, int N, int K)
{
    __shared__ unsigned short sa[128 * 32];
    __shared__ unsigned short sb[128 * 32];
    const int tid = threadIdx.x;
    const int lane = tid & 63;
    const int wave = tid >> 6;
    const int wr = wave >> 1, wc = wave & 1;

    int bx = blockIdx.x, by = blockIdx.y;
    if (SWZ) {
        const int nx = gridDim.x;
        const int nwg = nx * gridDim.y;
        const int lid = by * nx + bx;
        const int q = nwg >> 3;               // requires nwg % 8 == 0
        const int lid2 = (lid & 7) * q + (lid >> 3);
        by = lid2 / nx; bx = lid2 - by * nx;
    }
    const int m0 = by * 128;
    const int n0 = bx * 128;

    const int c0a = (wave * 2) * 64 + lane;
    const int c1a = (wave * 2 + 1) * 64 + lane;
    const int r0 = c0a >> 2, kk0 = (c0a & 3) * 8;
    const int r1 = c1a >> 2, kk1 = (c1a & 3) * 8;
    const unsigned short* ga0 = A  + (size_t)(m0 + r0) * K + kk0;
    const unsigned short* ga1 = A  + (size_t)(m0 + r1) * K + kk1;
    const unsigned short* gb0 = Bt + (size_t)(n0 + r0) * K + kk0;
    const unsigned short* gb1 = Bt + (size_t)(n0 + r1) * K + kk1;
    unsigned short* la0 = &sa[(wave * 2) * 512];
    unsigned short* la1 = &sa[(wave * 2 + 1) * 512];
    unsigned short* lb0 = &sb[(wave * 2) * 512];
    unsigned short* lb1 = &sb[(wave * 2 + 1) * 512];

    f32x4 acc[4][4] = {};
    const int kro = (lane >> 4) * 8;
    const int fr = lane & 15;

    for (int k0 = 0; k0 < K; k0 += 32) {
        __syncthreads();
        stage16(ga0 + k0, la0);
        stage16(ga1 + k0, la1);
        stage16(gb0 + k0, lb0);
        stage16(gb1 + k0, lb1);
        __syncthreads();
        bf16x8 af[4], bfr[4];
        #pragma unroll
        for (int i = 0; i < 4; ++i) {
            af[i]  = *reinterpret_cast<const bf16x8*>(&sa[(wr * 64 + i * 16 + fr) * 32 + kro]);
            bfr[i] = *reinterpret_cast<const bf16x8*>(&sb[(wc * 64 + i * 16 + fr) * 32 + kro]);
        }
        #pragma unroll
        for (int mi = 0; mi < 4; ++mi)
            #pragma unroll
            for (int ni = 0; ni < 4; ++ni)
                acc[mi][ni] = __builtin_amdgcn_mfma_f32_16x16x32_bf16(af[mi], bfr[ni], acc[mi][ni], 0, 0, 0);
    }

    #pragma unroll
    for (int mi = 0; mi < 4; ++mi) {
        #pragma unroll
        for (int ni = 0; ni < 4; ++ni) {
            const int gc = n0 + wc * 64 + ni * 16 + fr;
            const float bv = (MODE != 0) ? bias[gc] : 0.f;
            #pragma unroll
            for (int r = 0; r < 4; ++r) {
                const int gr = m0 + wr * 64 + mi * 16 + (lane >> 4) * 4 + r;
                float v = acc[mi][ni][r] + bv;
                if (MODE == 1) v += resid[(size_t)gr * N + gc];
                if (MODE == 2) v = fmaxf(v, 0.f);
                if (MODE == 0 || MODE == 2) {
                    ((unsigned short*)outp)[(size_t)gr * N + gc] = f2bf(v);
                } else {
                    ((float*)outp)[(size_t)gr * N + gc] = v;
                }
            }
        }
    }
}

// ---------------------------------------------------------------- sparse attention v3
// qkv [MROWS][1536] bf16. Block = 16 queries of one (b,h); window K/V in LDS
// (K XOR-swizzled); branchless scores; ballot-compacted global/random cols;
// cooperative coalesced QK-B dots; zero barriers in the query loop.
__global__ __launch_bounds__(256) void attn_kernel(
    const unsigned short* __restrict__ qkv, const int* __restrict__ rc,
    unsigned short* __restrict__ attnout)
{
    __shared__ unsigned short Kw[80 * 64];   // swizzled 16B chunks
    __shared__ unsigned short Vw[80 * 64];   // linear
    __shared__ int cwCol[4][64];             // compacted B-cols, per wave

    const int tid = threadIdx.x;
    const int wave = tid >> 6, lane = tid & 63;
    const int bid = blockIdx.x;
    const int tb = bid & 127;            // T/QB = 128
    const int h = (bid >> 7) & 7;
    const int b = bid >> 10;
    const int t0 = tb * QB;
    const int base = t0 - 63;

    const unsigned short* kb = qkv + (size_t)b * SEQT * 1536 + 512 + h * 64;
    const unsigned short* vb = qkv + (size_t)b * SEQT * 1536 + 1024 + h * 64;

    // stage window rows [base, t0+15] (79 rows): K swizzled, V linear
    for (int c = tid; c < 79 * 8; c += 256) {
        const int r = c >> 3, j = c & 7;
        const int col = base + r;
        u16x8 kv = {0, 0, 0, 0, 0, 0, 0, 0};
        u16x8 vv = {0, 0, 0, 0, 0, 0, 0, 0};
        if (col >= 0) {
            kv = *(const u16x8*)&kb[(size_t)col * 1536 + j * 8];
            vv = *(const u16x8*)&vb[(size_t)col * 1536 + j * 8];
        }
        *(u16x8*)&Kw[r * 64 + ((j ^ (r & 7)) * 8)] = kv;
        *(u16x8*)&Vw[r * 64 + j * 8] = vv;
    }
    __syncthreads();

    for (int u = 0; u < 4; ++u) {
        const int Q = wave * 4 + u;
        const int t = t0 + Q;
        const int m = b * SEQT + t;

        // per-lane Q element (dim = lane) for cooperative B dots
        const float qd = bf2f(qkv[(size_t)m * 1536 + h * 64 + lane]);
        // full Q row (wave-uniform, L1-broadcast) for window dots
        u16x8 qreg[8];
        #pragma unroll
        for (int j = 0; j < 8; ++j)
            qreg[j] = *(const u16x8*)&qkv[(size_t)m * 1536 + h * 64 + j * 8];

        // ---- window scores (slot A), branchless
        const int row = Q + lane;            // 0..78, always safe
        const int colA = base + row;
        float sA;
        {
            float s = 0.f;
            #pragma unroll
            for (int j = 0; j < 8; ++j) {
                const u16x8 kc = *(const u16x8*)&Kw[row * 64 + ((j ^ (row & 7)) * 8)];
                #pragma unroll
                for (int e = 0; e < 8; ++e)
                    s += bf2f(kc[e]) * bf2f(qreg[j][e]);
            }
            sA = (colA >= NGLOB) ? s * 0.125f : -1e30f;
        }

        // ---- candidate B-cols: lanes 0..15 global, 16..31 random; dedup via shfl
        int colB = 0;
        bool vB = false;
        if (lane < NGLOB) {
            colB = lane;
            vB = (lane <= t);
        } else if (lane < 32) {
            colB = rc[((size_t)h * SEQT + t) * NRAND + (lane - 16)];
            vB = (colB >= NGLOB) && (colB <= t - WIN);
        }
        #pragma unroll
        for (int j = 0; j < 15; ++j) {
            const int cj = __shfl(colB, 16 + j);
            if (lane >= 16 && lane < 32 && (lane - 16) > j && cj == colB) vB = false;
        }

        // ---- ballot-compact valid cols into per-wave LDS list
        const unsigned long long bm = __ballot(vB);
        const int nB = __popcll(bm);
        const int pos = __popcll(bm & ((1ull << lane) - 1ull));
        if (vB) cwCol[wave][pos] = colB;
        // same-wave LDS write->read: lgkmcnt ordering, no barrier needed

        // ---- cooperative QK-B: per compacted col, coalesced K-row + butterfly dot
        float sB = -1e30f;
        int i = 0;
        for (; i + 3 < nB; i += 4) {
            float p0 = qd * bf2f(kb[(size_t)cwCol[wave][i + 0] * 1536 + lane]);
            float p1 = qd * bf2f(kb[(size_t)cwCol[wave][i + 1] * 1536 + lane]);
            float p2 = qd * bf2f(kb[(size_t)cwCol[wave][i + 2] * 1536 + lane]);
            float p3 = qd * bf2f(kb[(size_t)cwCol[wave][i + 3] * 1536 + lane]);
            #pragma unroll
            for (int off = 32; off > 0; off >>= 1) {
                p0 += __shfl_xor(p0, off);
                p1 += __shfl_xor(p1, off);
                p2 += __shfl_xor(p2, off);
                p3 += __shfl_xor(p3, off);
            }
            sB = (lane == i + 0) ? p0 * 0.125f : sB;
            sB = (lane == i + 1) ? p1 * 0.125f : sB;
            sB = (lane == i + 2) ? p2 * 0.125f : sB;
            sB = (lane == i + 3) ? p3 * 0.125f : sB;
        }
        for (; i < nB; ++i) {
            float p = qd * bf2f(kb[(size_t)cwCol[wave][i] * 1536 + lane]);
            #pragma unroll
            for (int off = 32; off > 0; off >>= 1) p += __shfl_xor(p, off);
            if (lane == i) sB = p * 0.125f;
        }

        // ---- softmax across the wave (A in lane slots, B in lanes < nB)
        float mx = fmaxf(sA, sB);
        #pragma unroll
        for (int off = 32; off > 0; off >>= 1) mx = fmaxf(mx, __shfl_xor(mx, off));
        const float e0 = __expf(sA - mx);    // sA=-1e30 -> 0
        const float e1 = __expf(sB - mx);    // lanes >= nB: sB=-1e30 -> 0
        float sum = e0 + e1;
        #pragma unroll
        for (int off = 32; off > 0; off >>= 1) sum += __shfl_xor(sum, off);
        const float inv = 1.f / sum;

        // ---- PV: window from LDS (branch-free) + compacted B (pipelined)
        float acc = 0.f;
        #pragma unroll 8
        for (int s = 0; s < 64; ++s)
            acc += __shfl(e0, s) * bf2f(Vw[(Q + s) * 64 + lane]);
        for (int i2 = 0; i2 < nB; ++i2)
            acc += __shfl(e1, i2) * bf2f(vb[(size_t)cwCol[wave][i2] * 1536 + lane]);

        attnout[(size_t)m * CEMB + h * 64 + lane] = f2bf(acc * inv);
    }
}

// ---------------------------------------------------------------- host
extern "C" void kernel_launch(void* const* d_in, const int* in_sizes, int n_in,
                              void* d_out, int out_size, void* d_ws, size_t ws_size,
                              hipStream_t stream)
{
    const float* tok_emb = (const float*)d_in[0];
    const float* pos_emb = (const float*)d_in[1];
    const float* Wq    = (const float*)d_in[2];
    const float* Wk    = (const float*)d_in[3];
    const float* Wv    = (const float*)d_in[4];
    const float* Wproj = (const float*)d_in[5];
    const float* bproj = (const float*)d_in[6];
    const float* ln1g  = (const float*)d_in[7];
    const float* ln1b  = (const float*)d_in[8];
    const float* ln2g  = (const float*)d_in[9];
    const float* ln2b  = (const float*)d_in[10];
    const float* W1    = (const float*)d_in[11];
    const float* b1    = (const float*)d_in[12];
    const float* W2    = (const float*)d_in[13];
    const float* b2    = (const float*)d_in[14];
    const float* lnfg  = (const float*)d_in[15];
    const float* lnfb  = (const float*)d_in[16];
    const float* Wout  = (const float*)d_in[17];
    const float* bout  = (const float*)d_in[18];
    const int*   toks  = (const int*)d_in[19];
    const int*   rcols = (const int*)d_in[20];
    (void)in_sizes; (void)n_in; (void)out_size; (void)ws_size;

    char* ws = (char*)d_ws;
    size_t off = 0;
    auto ALLOC = [&](size_t bytes) -> void* {
        void* p = ws + off;
        off += (bytes + 255) & ~(size_t)255;
        return p;
    };
    float*          x      = (float*)ALLOC((size_t)MROWS * CEMB * 4);
    unsigned short* xnbf   = (unsigned short*)ALLOC((size_t)MROWS * CEMB * 2);
    unsigned short* qkv    = (unsigned short*)ALLOC((size_t)MROWS * 1536 * 2);
    unsigned short* attnbf = (unsigned short*)ALLOC((size_t)MROWS * CEMB * 2);
    unsigned short* hbf    = (unsigned short*)ALLOC((size_t)MROWS * 2048 * 2);
    unsigned short* wqkvT  = (unsigned short*)ALLOC((size_t)NLAYER * 1536 * 512 * 2);
    unsigned short* wprojT = (unsigned short*)ALLOC((size_t)NLAYER * 512 * 512 * 2);
    unsigned short* w1T    = (unsigned short*)ALLOC((size_t)NLAYER * 2048 * 512 * 2);
    unsigned short* w2T    = (unsigned short*)ALLOC((size_t)NLAYER * 512 * 2048 * 2);
    unsigned short* woutT  = (unsigned short*)ALLOC((size_t)VOCAB_N * 512 * 2);

    transpose_qkv_kernel<<<dim3(8, 24, NLAYER), 256, 0, stream>>>(Wq, Wk, Wv, wqkvT);
    transpose_mat_kernel<<<dim3(8, 8, NLAYER),  256, 0, stream>>>(Wproj, wprojT, 512, 512);
    transpose_mat_kernel<<<dim3(8, 32, NLAYER), 256, 0, stream>>>(W1, w1T, 512, 2048);
    transpose_mat_kernel<<<dim3(32, 8, NLAYER), 256, 0, stream>>>(W2, w2T, 2048, 512);
    transpose_mat_kernel<<<dim3(8, 500, 1),     256, 0, stream>>>(Wout, woutT, 512, VOCAB_N);

    embed_kernel<<<2048, 256, 0, stream>>>(tok_emb, pos_emb, toks, x);

    for (int l = 0; l < NLAYER; ++l) {
        ln_kernel<<<1024, 256, 0, stream>>>(x, ln1g + l * CEMB, ln1b + l * CEMB, xnbf);
        gemm_kernel<0, false><<<dim3(12, 32), 256, 0, stream>>>(
            xnbf, wqkvT + (size_t)l * 1536 * 512, nullptr, nullptr, qkv, MROWS, 1536, 512);
        attn_kernel<<<2048, 256, 0, stream>>>(qkv, rcols + (size_t)l * NHEAD * SEQT * NRAND, attnbf);
        gemm_kernel<1, false><<<dim3(4, 32), 256, 0, stream>>>(
            attnbf, wprojT + (size_t)l * 512 * 512, bproj + l * CEMB, x, x, MROWS, 512, 512);
        ln_kernel<<<1024, 256, 0, stream>>>(x, ln2g + l * CEMB, ln2b + l * CEMB, xnbf);
        gemm_kernel<2, false><<<dim3(16, 32), 256, 0, stream>>>(
            xnbf, w1T + (size_t)l * 2048 * 512, b1 + l * 2048, nullptr, hbf, MROWS, 2048, 512);
        gemm_kernel<1, false><<<dim3(4, 32), 256, 0, stream>>>(
            hbf, w2T + (size_t)l * 512 * 2048, b2 + l * CEMB, x, x, MROWS, 512, 2048);
    }
    ln_kernel<<<1024, 256, 0, stream>>>(x, lnfg, lnfb, xnbf);
    gemm_kernel<3, true><<<dim3(250, 32), 256, 0, stream>>>(
        xnbf, woutT, bout, nullptr, d_out, MROWS, VOCAB_N, 512);
}

// Round 5
// 1136.069 us; speedup vs baseline: 1.2441x; 1.2441x over previous
//
#include <hip/hip_runtime.h>
#include <hip/hip_bf16.h>

#define NLAYER 4
#define NHEAD 8
#define CEMB 512
#define HS 64
#define VOCAB_N 32000
#define SEQT 2048
#define BATCH_N 2
#define MROWS (BATCH_N * SEQT)   /* 4096 */
#define WIN 64
#define NGLOB 16
#define NRAND 16
#define QB 16                    /* queries per attention block */

typedef __attribute__((ext_vector_type(8))) __bf16 bf16x8;
typedef __attribute__((ext_vector_type(4))) float f32x4;
typedef __attribute__((ext_vector_type(8))) unsigned short u16x8;

__device__ __forceinline__ unsigned short f2bf(float f) {
    unsigned u = __float_as_uint(f);
    u += 0x7fffu + ((u >> 16) & 1u);      // RNE
    return (unsigned short)(u >> 16);
}
__device__ __forceinline__ float bf2f(unsigned short v) {
    return __uint_as_float((unsigned)v << 16);
}

// async global->LDS, 16B per lane, dest = wave-uniform base + lane*16
__device__ __forceinline__ void stage16(const unsigned short* g, unsigned short* l) {
    __builtin_amdgcn_global_load_lds(
        (const __attribute__((address_space(1))) void*)g,
        (__attribute__((address_space(3))) void*)l, 16, 0, 0);
}

// ---------------------------------------------------------------- unified weight transpose
// One dispatch for all 5 weight transposes (launch-count probe).
// Generic 64x64 tile: dst[(n0+c)*Ks + k0+r] = bf16(src[(k0+r)*Ns + n0+c])
__global__ __launch_bounds__(256) void transpose_all_kernel(
    const float* __restrict__ Wq, const float* __restrict__ Wk,
    const float* __restrict__ Wv, const float* __restrict__ Wproj,
    const float* __restrict__ W1, const float* __restrict__ W2,
    const float* __restrict__ Wout,
    unsigned short* __restrict__ wqkvT, unsigned short* __restrict__ wprojT,
    unsigned short* __restrict__ w1T, unsigned short* __restrict__ w2T,
    unsigned short* __restrict__ woutT)
{
    __shared__ float tle[64][65];
    const int bid = blockIdx.x;
    const float* src; unsigned short* dst; int Ks, Ns, k0, n0;
    if (bid < 768) {                       // Wq/Wk/Wv: [C=512,HS=64] -> [64,512] per (l,sel,h)
        const int tile = bid & 7, rest = bid >> 3;       // rest < 96
        const int l = rest / 24, r2 = rest % 24;
        const int sel = r2 >> 3, h = r2 & 7;
        const float* W = (sel == 0) ? Wq : (sel == 1) ? Wk : Wv;
        src = W + (size_t)(l * 8 + h) * 512 * 64;
        dst = wqkvT + ((size_t)l * 1536 + sel * 512 + h * 64) * 512;
        Ks = 512; Ns = 64; k0 = tile * 64; n0 = 0;
    } else if (bid < 1024) {               // Wproj [512,512] x4
        const int idx = bid - 768, l = idx >> 6, t6 = idx & 63;
        src = Wproj + (size_t)l * 512 * 512;
        dst = wprojT + (size_t)l * 512 * 512;
        Ks = 512; Ns = 512; k0 = (t6 >> 3) * 64; n0 = (t6 & 7) * 64;
    } else if (bid < 2048) {               // W1 [512,2048] x4
        const int idx = bid - 1024, l = idx >> 8, t8 = idx & 255;
        src = W1 + (size_t)l * 512 * 2048;
        dst = w1T + (size_t)l * 2048 * 512;
        Ks = 512; Ns = 2048; k0 = (t8 >> 5) * 64; n0 = (t8 & 31) * 64;
    } else if (bid < 3072) {               // W2 [2048,512] x4
        const int idx = bid - 2048, l = idx >> 8, t8 = idx & 255;
        src = W2 + (size_t)l * 2048 * 512;
        dst = w2T + (size_t)l * 512 * 2048;
        Ks = 2048; Ns = 512; k0 = (t8 >> 3) * 64; n0 = (t8 & 7) * 64;
    } else {                               // Wout [512,32000]
        const int idx = bid - 3072;        // 0..3999
        src = Wout; dst = woutT;
        Ks = 512; Ns = 32000; k0 = (idx / 500) * 64; n0 = (idx % 500) * 64;
    }
    const int tid = threadIdx.x;
    #pragma unroll
    for (int i = 0; i < 16; ++i) {
        const int idx = tid + i * 256;
        const int r = idx >> 6, c = idx & 63;
        tle[r][c] = src[(size_t)(k0 + r) * Ns + n0 + c];
    }
    __syncthreads();
    #pragma unroll
    for (int i = 0; i < 16; ++i) {
        const int idx = tid + i * 256;
        const int c = idx >> 6, r = idx & 63;
        dst[(size_t)(n0 + c) * Ks + k0 + r] = f2bf(tle[r][c]);
    }
}

// ---------------------------------------------------------------- embedding
__global__ __launch_bounds__(256) void embed_kernel(
    const float* __restrict__ tok_emb, const float* __restrict__ pos_emb,
    const int* __restrict__ toks, float* __restrict__ x)
{
    int i = blockIdx.x * 256 + threadIdx.x;
    int m = i >> 7;
    int c = (i & 127) << 2;
    int tok = toks[m];
    const float4 a = *(const float4*)&tok_emb[(size_t)tok * CEMB + c];
    const float4 p = *(const float4*)&pos_emb[(size_t)(m & (SEQT - 1)) * CEMB + c];
    float4 o;
    o.x = a.x + p.x; o.y = a.y + p.y; o.z = a.z + p.z; o.w = a.w + p.w;
    *(float4*)&x[(size_t)m * CEMB + c] = o;
}

// ---------------------------------------------------------------- layernorm
__global__ __launch_bounds__(256) void ln_kernel(
    const float* __restrict__ x, const float* __restrict__ g,
    const float* __restrict__ b, unsigned short* __restrict__ out)
{
    const int wave = threadIdx.x >> 6, lane = threadIdx.x & 63;
    const int m = blockIdx.x * 4 + wave;
    const float* row = x + (size_t)m * CEMB;
    const float4 v0 = *(const float4*)&row[lane * 8];
    const float4 v1 = *(const float4*)&row[lane * 8 + 4];
    float s  = v0.x + v0.y + v0.z + v0.w + v1.x + v1.y + v1.z + v1.w;
    float s2 = v0.x*v0.x + v0.y*v0.y + v0.z*v0.z + v0.w*v0.w
             + v1.x*v1.x + v1.y*v1.y + v1.z*v1.z + v1.w*v1.w;
    #pragma unroll
    for (int off = 32; off > 0; off >>= 1) {
        s  += __shfl_xor(s, off);
        s2 += __shfl_xor(s2, off);
    }
    const float mu  = s * (1.f / CEMB);
    const float var = s2 * (1.f / CEMB) - mu * mu;
    const float rs  = rsqrtf(var + 1e-5f);
    const float vals[8] = {v0.x, v0.y, v0.z, v0.w, v1.x, v1.y, v1.z, v1.w};
    u16x8 o;
    #pragma unroll
    for (int j = 0; j < 8; ++j)
        o[j] = f2bf((vals[j] - mu) * rs * g[lane * 8 + j] + b[lane * 8 + j]);
    *(u16x8*)&out[(size_t)m * CEMB + lane * 8] = o;
}

// ---------------------------------------------------------------- MFMA GEMM (m97 structure)
// MODE 0: bf16 out, no bias           (qkv)
// MODE 1: f32 out, +bias, +resid      (proj, mlp2)
// MODE 2: bf16 out, +bias, relu       (mlp1)
// MODE 3: f32 out, +bias              (logits)
template<int MODE, bool SWZ>
__global__ __launch_bounds__(256) void gemm_kernel(
    const unsigned short* __restrict__ A, const unsigned short* __restrict__ Bt,
    const float* __restrict__ bias, const float* resid, void* outp,
    int M, int N, int K)
{
    __shared__ unsigned short sa[128 * 32];
    __shared__ unsigned short sb[128 * 32];
    const int tid = threadIdx.x;
    const int lane = tid & 63;
    const int wave = tid >> 6;
    const int wr = wave >> 1, wc = wave & 1;

    int bx = blockIdx.x, by = blockIdx.y;
    if (SWZ) {
        const int nx = gridDim.x;
        const int nwg = nx * gridDim.y;
        const int lid = by * nx + bx;
        const int q = nwg >> 3;               // requires nwg % 8 == 0
        const int lid2 = (lid & 7) * q + (lid >> 3);
        by = lid2 / nx; bx = lid2 - by * nx;
    }
    const int m0 = by * 128;
    const int n0 = bx * 128;

    const int c0a = (wave * 2) * 64 + lane;
    const int c1a = (wave * 2 + 1) * 64 + lane;
    const int r0 = c0a >> 2, kk0 = (c0a & 3) * 8;
    const int r1 = c1a >> 2, kk1 = (c1a & 3) * 8;
    const unsigned short* ga0 = A  + (size_t)(m0 + r0) * K + kk0;
    const unsigned short* ga1 = A  + (size_t)(m0 + r1) * K + kk1;
    const unsigned short* gb0 = Bt + (size_t)(n0 + r0) * K + kk0;
    const unsigned short* gb1 = Bt + (size_t)(n0 + r1) * K + kk1;
    unsigned short* la0 = &sa[(wave * 2) * 512];
    unsigned short* la1 = &sa[(wave * 2 + 1) * 512];
    unsigned short* lb0 = &sb[(wave * 2) * 512];
    unsigned short* lb1 = &sb[(wave * 2 + 1) * 512];

    f32x4 acc[4][4] = {};
    const int kro = (lane >> 4) * 8;
    const int fr = lane & 15;

    for (int k0 = 0; k0 < K; k0 += 32) {
        __syncthreads();
        stage16(ga0 + k0, la0);
        stage16(ga1 + k0, la1);
        stage16(gb0 + k0, lb0);
        stage16(gb1 + k0, lb1);
        __syncthreads();
        bf16x8 af[4], bfr[4];
        #pragma unroll
        for (int i = 0; i < 4; ++i) {
            af[i]  = *reinterpret_cast<const bf16x8*>(&sa[(wr * 64 + i * 16 + fr) * 32 + kro]);
            bfr[i] = *reinterpret_cast<const bf16x8*>(&sb[(wc * 64 + i * 16 + fr) * 32 + kro]);
        }
        #pragma unroll
        for (int mi = 0; mi < 4; ++mi)
            #pragma unroll
            for (int ni = 0; ni < 4; ++ni)
                acc[mi][ni] = __builtin_amdgcn_mfma_f32_16x16x32_bf16(af[mi], bfr[ni], acc[mi][ni], 0, 0, 0);
    }

    #pragma unroll
    for (int mi = 0; mi < 4; ++mi) {
        #pragma unroll
        for (int ni = 0; ni < 4; ++ni) {
            const int gc = n0 + wc * 64 + ni * 16 + fr;
            const float bv = (MODE != 0) ? bias[gc] : 0.f;
            #pragma unroll
            for (int r = 0; r < 4; ++r) {
                const int gr = m0 + wr * 64 + mi * 16 + (lane >> 4) * 4 + r;
                float v = acc[mi][ni][r] + bv;
                if (MODE == 1) v += resid[(size_t)gr * N + gc];
                if (MODE == 2) v = fmaxf(v, 0.f);
                if (MODE == 0 || MODE == 2) {
                    ((unsigned short*)outp)[(size_t)gr * N + gc] = f2bf(v);
                } else {
                    ((float*)outp)[(size_t)gr * N + gc] = v;
                }
            }
        }
    }
}

// ---------------------------------------------------------------- sparse attention v2.5
// = round-3 v2 structure (scattered per-lane QK-B dots, LDS weights), plus:
//   - no per-query barriers (all cross-lane data is per-wave LDS)
//   - ballot-compacted PV-B list, padded to x4, branch-free 4-wide body
//   - shfl-based random-col dedup
__global__ __launch_bounds__(256) void attn_kernel(
    const unsigned short* __restrict__ qkv, const int* __restrict__ rc,
    unsigned short* __restrict__ attnout)
{
    __shared__ unsigned short Kw[80 * 64];   // swizzled 16B chunks
    __shared__ unsigned short Vw[80 * 64];   // linear
    __shared__ float ewA[4][64];             // window weights (per wave)
    __shared__ float cwW[4][40];             // compacted B weights (per wave)
    __shared__ int   cwC[4][40];             // compacted B cols   (per wave)

    const int tid = threadIdx.x;
    const int wave = tid >> 6, lane = tid & 63;
    const int bid = blockIdx.x;
    const int tb = bid & 127;            // T/QB = 128
    const int h = (bid >> 7) & 7;
    const int b = bid >> 10;
    const int t0 = tb * QB;
    const int base = t0 - 63;

    const unsigned short* kb = qkv + (size_t)b * SEQT * 1536 + 512 + h * 64;
    const unsigned short* vb = qkv + (size_t)b * SEQT * 1536 + 1024 + h * 64;

    // stage window rows [base, t0+15] (79 rows): K swizzled, V linear
    for (int c = tid; c < 79 * 8; c += 256) {
        const int r = c >> 3, j = c & 7;
        const int col = base + r;
        u16x8 kv = {0, 0, 0, 0, 0, 0, 0, 0};
        u16x8 vv = {0, 0, 0, 0, 0, 0, 0, 0};
        if (col >= 0) {
            kv = *(const u16x8*)&kb[(size_t)col * 1536 + j * 8];
            vv = *(const u16x8*)&vb[(size_t)col * 1536 + j * 8];
        }
        *(u16x8*)&Kw[r * 64 + ((j ^ (r & 7)) * 8)] = kv;
        *(u16x8*)&Vw[r * 64 + j * 8] = vv;
    }
    __syncthreads();

    for (int u = 0; u < 4; ++u) {
        const int Q = wave * 4 + u;
        const int t = t0 + Q;
        const int m = b * SEQT + t;

        // Q row (wave-uniform, L1-broadcast) in regs
        u16x8 qreg[8];
        #pragma unroll
        for (int j = 0; j < 8; ++j)
            qreg[j] = *(const u16x8*)&qkv[(size_t)m * 1536 + h * 64 + j * 8];

        // ---- window score (slot A): LDS K row, branchless compute + select
        const int row = Q + lane;            // 0..78, always safe
        const int colA = base + row;
        float sA;
        {
            float s = 0.f;
            #pragma unroll
            for (int j = 0; j < 8; ++j) {
                const u16x8 kc = *(const u16x8*)&Kw[row * 64 + ((j ^ (row & 7)) * 8)];
                #pragma unroll
                for (int e = 0; e < 8; ++e)
                    s += bf2f(kc[e]) * bf2f(qreg[j][e]);
            }
            sA = (colA >= NGLOB) ? s * 0.125f : -1e30f;
        }

        // ---- B candidates: lanes 0..15 global, 16..31 random; shfl dedup
        int colB = 0;
        bool vB = false;
        if (lane < NGLOB) {
            colB = lane;
            vB = (lane <= t);
        } else if (lane < 32) {
            colB = rc[((size_t)h * SEQT + t) * NRAND + (lane - 16)];
            vB = (colB >= NGLOB) && (colB <= t - WIN);
        }
        #pragma unroll
        for (int j = 0; j < 15; ++j) {
            const int cj = __shfl(colB, 16 + j);
            if (lane >= 16 && lane < 32 && (lane - 16) > j && cj == colB) vB = false;
        }

        // ---- per-lane scattered QK-B dot (16 global + <=16 random lanes, parallel)
        float sB = -1e30f;
        if (vB) {
            float s = 0.f;
            const unsigned short* kr = &kb[(size_t)colB * 1536];
            #pragma unroll
            for (int j = 0; j < 8; ++j) {
                const u16x8 kc = *(const u16x8*)&kr[j * 8];
                #pragma unroll
                for (int e = 0; e < 8; ++e)
                    s += bf2f(kc[e]) * bf2f(qreg[j][e]);
            }
            sB = s * 0.125f;
        }

        // ---- softmax across the wave
        float mx = fmaxf(sA, sB);
        #pragma unroll
        for (int off = 32; off > 0; off >>= 1) mx = fmaxf(mx, __shfl_xor(mx, off));
        const float e0 = (colA >= NGLOB) ? __expf(sA - mx) : 0.f;
        const float e1 = vB ? __expf(sB - mx) : 0.f;
        float sum = e0 + e1;
        #pragma unroll
        for (int off = 32; off > 0; off >>= 1) sum += __shfl_xor(sum, off);
        const float inv = 1.f / sum;

        // ---- stash weights (per-wave LDS; same-wave write->read, no barrier)
        ewA[wave][lane] = e0;
        const unsigned long long bm = __ballot(vB);
        const int nB = __popcll(bm);
        const int pos = __popcll(bm & ((1ull << lane) - 1ull));
        if (vB) { cwC[wave][pos] = colB; cwW[wave][pos] = e1; }
        if (lane >= 32 && lane < 36) {       // pad to multiple of 4 (nB <= 32)
            const int p = nB + (lane - 32);
            cwC[wave][p] = 0; cwW[wave][p] = 0.f;
        }

        // ---- PV window: LDS V, branch-free
        float acc = 0.f;
        #pragma unroll 8
        for (int s = 0; s < 64; ++s)
            acc += ewA[wave][s] * bf2f(Vw[(Q + s) * 64 + lane]);

        // ---- PV-B: compacted, 4-wide branch-free (4 loads in flight)
        const int nB4 = (nB + 3) & ~3;
        for (int i = 0; i < nB4; i += 4) {
            const float w0 = cwW[wave][i + 0], w1 = cwW[wave][i + 1];
            const float w2 = cwW[wave][i + 2], w3 = cwW[wave][i + 3];
            const int   c0 = cwC[wave][i + 0], c1 = cwC[wave][i + 1];
            const int   c2 = cwC[wave][i + 2], c3 = cwC[wave][i + 3];
            const float x0 = bf2f(vb[(size_t)c0 * 1536 + lane]);
            const float x1 = bf2f(vb[(size_t)c1 * 1536 + lane]);
            const float x2 = bf2f(vb[(size_t)c2 * 1536 + lane]);
            const float x3 = bf2f(vb[(size_t)c3 * 1536 + lane]);
            acc += w0 * x0 + w1 * x1 + w2 * x2 + w3 * x3;
        }

        attnout[(size_t)m * CEMB + h * 64 + lane] = f2bf(acc * inv);
    }
}

// ---------------------------------------------------------------- host
extern "C" void kernel_launch(void* const* d_in, const int* in_sizes, int n_in,
                              void* d_out, int out_size, void* d_ws, size_t ws_size,
                              hipStream_t stream)
{
    const float* tok_emb = (const float*)d_in[0];
    const float* pos_emb = (const float*)d_in[1];
    const float* Wq    = (const float*)d_in[2];
    const float* Wk    = (const float*)d_in[3];
    const float* Wv    = (const float*)d_in[4];
    const float* Wproj = (const float*)d_in[5];
    const float* bproj = (const float*)d_in[6];
    const float* ln1g  = (const float*)d_in[7];
    const float* ln1b  = (const float*)d_in[8];
    const float* ln2g  = (const float*)d_in[9];
    const float* ln2b  = (const float*)d_in[10];
    const float* W1    = (const float*)d_in[11];
    const float* b1    = (const float*)d_in[12];
    const float* W2    = (const float*)d_in[13];
    const float* b2    = (const float*)d_in[14];
    const float* lnfg  = (const float*)d_in[15];
    const float* lnfb  = (const float*)d_in[16];
    const float* Wout  = (const float*)d_in[17];
    const float* bout  = (const float*)d_in[18];
    const int*   toks  = (const int*)d_in[19];
    const int*   rcols = (const int*)d_in[20];
    (void)in_sizes; (void)n_in; (void)out_size; (void)ws_size;

    char* ws = (char*)d_ws;
    size_t off = 0;
    auto ALLOC = [&](size_t bytes) -> void* {
        void* p = ws + off;
        off += (bytes + 255) & ~(size_t)255;
        return p;
    };
    float*          x      = (float*)ALLOC((size_t)MROWS * CEMB * 4);
    unsigned short* xnbf   = (unsigned short*)ALLOC((size_t)MROWS * CEMB * 2);
    unsigned short* qkv    = (unsigned short*)ALLOC((size_t)MROWS * 1536 * 2);
    unsigned short* attnbf = (unsigned short*)ALLOC((size_t)MROWS * CEMB * 2);
    unsigned short* hbf    = (unsigned short*)ALLOC((size_t)MROWS * 2048 * 2);
    unsigned short* wqkvT  = (unsigned short*)ALLOC((size_t)NLAYER * 1536 * 512 * 2);
    unsigned short* wprojT = (unsigned short*)ALLOC((size_t)NLAYER * 512 * 512 * 2);
    unsigned short* w1T    = (unsigned short*)ALLOC((size_t)NLAYER * 2048 * 512 * 2);
    unsigned short* w2T    = (unsigned short*)ALLOC((size_t)NLAYER * 512 * 2048 * 2);
    unsigned short* woutT  = (unsigned short*)ALLOC((size_t)VOCAB_N * 512 * 2);

    transpose_all_kernel<<<7072, 256, 0, stream>>>(
        Wq, Wk, Wv, Wproj, W1, W2, Wout, wqkvT, wprojT, w1T, w2T, woutT);

    embed_kernel<<<2048, 256, 0, stream>>>(tok_emb, pos_emb, toks, x);

    for (int l = 0; l < NLAYER; ++l) {
        ln_kernel<<<1024, 256, 0, stream>>>(x, ln1g + l * CEMB, ln1b + l * CEMB, xnbf);
        gemm_kernel<0, false><<<dim3(12, 32), 256, 0, stream>>>(
            xnbf, wqkvT + (size_t)l * 1536 * 512, nullptr, nullptr, qkv, MROWS, 1536, 512);
        attn_kernel<<<2048, 256, 0, stream>>>(qkv, rcols + (size_t)l * NHEAD * SEQT * NRAND, attnbf);
        gemm_kernel<1, false><<<dim3(4, 32), 256, 0, stream>>>(
            attnbf, wprojT + (size_t)l * 512 * 512, bproj + l * CEMB, x, x, MROWS, 512, 512);
        ln_kernel<<<1024, 256, 0, stream>>>(x, ln2g + l * CEMB, ln2b + l * CEMB, xnbf);
        gemm_kernel<2, false><<<dim3(16, 32), 256, 0, stream>>>(
            xnbf, w1T + (size_t)l * 2048 * 512, b1 + l * 2048, nullptr, hbf, MROWS, 2048, 512);
        gemm_kernel<1, false><<<dim3(4, 32), 256, 0, stream>>>(
            hbf, w2T + (size_t)l * 512 * 2048, b2 + l * CEMB, x, x, MROWS, 512, 2048);
    }
    ln_kernel<<<1024, 256, 0, stream>>>(x, lnfg, lnfb, xnbf);
    gemm_kernel<3, true><<<dim3(250, 32), 256, 0, stream>>>(
        xnbf, woutT, bout, nullptr, d_out, MROWS, VOCAB_N, 512);
}

// Round 6
// 1069.732 us; speedup vs baseline: 1.3213x; 1.0620x over previous
//
#include <hip/hip_runtime.h>
#include <hip/hip_bf16.h>

#define NLAYER 4
#define NHEAD 8
#define CEMB 512
#define HS 64
#define VOCAB_N 32000
#define SEQT 2048
#define BATCH_N 2
#define MROWS (BATCH_N * SEQT)   /* 4096 */
#define WIN 64
#define NGLOB 16
#define NRAND 16
#define QB 16                    /* queries per attention block */

typedef __attribute__((ext_vector_type(8))) __bf16 bf16x8;
typedef __attribute__((ext_vector_type(4))) float f32x4;
typedef __attribute__((ext_vector_type(8))) unsigned short u16x8;

__device__ __forceinline__ unsigned short f2bf(float f) {
    unsigned u = __float_as_uint(f);
    u += 0x7fffu + ((u >> 16) & 1u);      // RNE
    return (unsigned short)(u >> 16);
}
__device__ __forceinline__ float bf2f(unsigned short v) {
    return __uint_as_float((unsigned)v << 16);
}

// async global->LDS, 16B per lane, dest = wave-uniform base + lane*16
__device__ __forceinline__ void stage16(const unsigned short* g, unsigned short* l) {
    __builtin_amdgcn_global_load_lds(
        (const __attribute__((address_space(1))) void*)g,
        (__attribute__((address_space(3))) void*)l, 16, 0, 0);
}

// ---------------------------------------------------------------- unified weight transpose
__global__ __launch_bounds__(256) void transpose_all_kernel(
    const float* __restrict__ Wq, const float* __restrict__ Wk,
    const float* __restrict__ Wv, const float* __restrict__ Wproj,
    const float* __restrict__ W1, const float* __restrict__ W2,
    const float* __restrict__ Wout,
    unsigned short* __restrict__ wqkvT, unsigned short* __restrict__ wprojT,
    unsigned short* __restrict__ w1T, unsigned short* __restrict__ w2T,
    unsigned short* __restrict__ woutT)
{
    __shared__ float tle[64][65];
    const int bid = blockIdx.x;
    const float* src; unsigned short* dst; int Ks, Ns, k0, n0;
    if (bid < 768) {                       // Wq/Wk/Wv: [C=512,HS=64] -> [64,512] per (l,sel,h)
        const int tile = bid & 7, rest = bid >> 3;       // rest < 96
        const int l = rest / 24, r2 = rest % 24;
        const int sel = r2 >> 3, h = r2 & 7;
        const float* W = (sel == 0) ? Wq : (sel == 1) ? Wk : Wv;
        src = W + (size_t)(l * 8 + h) * 512 * 64;
        dst = wqkvT + ((size_t)l * 1536 + sel * 512 + h * 64) * 512;
        Ks = 512; Ns = 64; k0 = tile * 64; n0 = 0;
    } else if (bid < 1024) {               // Wproj [512,512] x4
        const int idx = bid - 768, l = idx >> 6, t6 = idx & 63;
        src = Wproj + (size_t)l * 512 * 512;
        dst = wprojT + (size_t)l * 512 * 512;
        Ks = 512; Ns = 512; k0 = (t6 >> 3) * 64; n0 = (t6 & 7) * 64;
    } else if (bid < 2048) {               // W1 [512,2048] x4
        const int idx = bid - 1024, l = idx >> 8, t8 = idx & 255;
        src = W1 + (size_t)l * 512 * 2048;
        dst = w1T + (size_t)l * 2048 * 512;
        Ks = 512; Ns = 2048; k0 = (t8 >> 5) * 64; n0 = (t8 & 31) * 64;
    } else if (bid < 3072) {               // W2 [2048,512] x4
        const int idx = bid - 2048, l = idx >> 8, t8 = idx & 255;
        src = W2 + (size_t)l * 2048 * 512;
        dst = w2T + (size_t)l * 512 * 2048;
        Ks = 2048; Ns = 512; k0 = (t8 >> 3) * 64; n0 = (t8 & 7) * 64;
    } else {                               // Wout [512,32000]
        const int idx = bid - 3072;        // 0..3999
        src = Wout; dst = woutT;
        Ks = 512; Ns = 32000; k0 = (idx / 500) * 64; n0 = (idx % 500) * 64;
    }
    const int tid = threadIdx.x;
    #pragma unroll
    for (int i = 0; i < 16; ++i) {
        const int idx = tid + i * 256;
        const int r = idx >> 6, c = idx & 63;
        tle[r][c] = src[(size_t)(k0 + r) * Ns + n0 + c];
    }
    __syncthreads();
    #pragma unroll
    for (int i = 0; i < 16; ++i) {
        const int idx = tid + i * 256;
        const int c = idx >> 6, r = idx & 63;
        dst[(size_t)(n0 + c) * Ks + k0 + r] = f2bf(tle[r][c]);
    }
}

// ---------------------------------------------------------------- embedding
__global__ __launch_bounds__(256) void embed_kernel(
    const float* __restrict__ tok_emb, const float* __restrict__ pos_emb,
    const int* __restrict__ toks, float* __restrict__ x)
{
    int i = blockIdx.x * 256 + threadIdx.x;
    int m = i >> 7;
    int c = (i & 127) << 2;
    int tok = toks[m];
    const float4 a = *(const float4*)&tok_emb[(size_t)tok * CEMB + c];
    const float4 p = *(const float4*)&pos_emb[(size_t)(m & (SEQT - 1)) * CEMB + c];
    float4 o;
    o.x = a.x + p.x; o.y = a.y + p.y; o.z = a.z + p.z; o.w = a.w + p.w;
    *(float4*)&x[(size_t)m * CEMB + c] = o;
}

// ---------------------------------------------------------------- layernorm
__global__ __launch_bounds__(256) void ln_kernel(
    const float* __restrict__ x, const float* __restrict__ g,
    const float* __restrict__ b, unsigned short* __restrict__ out)
{
    const int wave = threadIdx.x >> 6, lane = threadIdx.x & 63;
    const int m = blockIdx.x * 4 + wave;
    const float* row = x + (size_t)m * CEMB;
    const float4 v0 = *(const float4*)&row[lane * 8];
    const float4 v1 = *(const float4*)&row[lane * 8 + 4];
    float s  = v0.x + v0.y + v0.z + v0.w + v1.x + v1.y + v1.z + v1.w;
    float s2 = v0.x*v0.x + v0.y*v0.y + v0.z*v0.z + v0.w*v0.w
             + v1.x*v1.x + v1.y*v1.y + v1.z*v1.z + v1.w*v1.w;
    #pragma unroll
    for (int off = 32; off > 0; off >>= 1) {
        s  += __shfl_xor(s, off);
        s2 += __shfl_xor(s2, off);
    }
    const float mu  = s * (1.f / CEMB);
    const float var = s2 * (1.f / CEMB) - mu * mu;
    const float rs  = rsqrtf(var + 1e-5f);
    const float vals[8] = {v0.x, v0.y, v0.z, v0.w, v1.x, v1.y, v1.z, v1.w};
    u16x8 o;
    #pragma unroll
    for (int j = 0; j < 8; ++j)
        o[j] = f2bf((vals[j] - mu) * rs * g[lane * 8 + j] + b[lane * 8 + j]);
    *(u16x8*)&out[(size_t)m * CEMB + lane * 8] = o;
}

// ---------------------------------------------------------------- MFMA GEMM, 2-phase pipelined
// Double-buffered LDS; STAGE(t+1) issued BEFORE compute(t); ONE __syncthreads
// per K-step (drains vmcnt for the prefetch + protects ds_reads). T3-lite.
// MODE 0: bf16 out, no bias           (qkv)
// MODE 1: f32 out, +bias, +resid      (proj, mlp2)
// MODE 2: bf16 out, +bias, relu       (mlp1)
// MODE 3: f32 out, +bias              (logits)
template<int MODE, bool SWZ>
__global__ __launch_bounds__(256) void gemm_kernel(
    const unsigned short* __restrict__ A, const unsigned short* __restrict__ Bt,
    const float* __restrict__ bias, const float* resid, void* outp,
    int M, int N, int K)
{
    __shared__ unsigned short sa[2][128 * 32];
    __shared__ unsigned short sb[2][128 * 32];
    const int tid = threadIdx.x;
    const int lane = tid & 63;
    const int wave = tid >> 6;
    const int wr = wave >> 1, wc = wave & 1;

    int bx = blockIdx.x, by = blockIdx.y;
    if (SWZ) {
        const int nx = gridDim.x;
        const int nwg = nx * gridDim.y;
        const int lid = by * nx + bx;
        const int q = nwg >> 3;               // requires nwg % 8 == 0
        const int lid2 = (lid & 7) * q + (lid >> 3);
        by = lid2 / nx; bx = lid2 - by * nx;
    }
    const int m0 = by * 128;
    const int n0 = bx * 128;

    // staging map: chunk c (16B) covers row=c/4, k=(c%4)*8. Wave w owns
    // segments {2w, 2w+1}; within a segment, lane i -> chunk seg*64+i.
    const int c0a = (wave * 2) * 64 + lane;
    const int c1a = (wave * 2 + 1) * 64 + lane;
    const int r0 = c0a >> 2, kk0 = (c0a & 3) * 8;
    const int r1 = c1a >> 2, kk1 = (c1a & 3) * 8;
    const unsigned short* ga0 = A  + (size_t)(m0 + r0) * K + kk0;
    const unsigned short* ga1 = A  + (size_t)(m0 + r1) * K + kk1;
    const unsigned short* gb0 = Bt + (size_t)(n0 + r0) * K + kk0;
    const unsigned short* gb1 = Bt + (size_t)(n0 + r1) * K + kk1;
    const int o0 = (wave * 2) * 512;
    const int o1 = (wave * 2 + 1) * 512;

    f32x4 acc[4][4] = {};
    const int kro = (lane >> 4) * 8;
    const int fr = lane & 15;

    // prologue: stage tile 0 into buffer 0
    stage16(ga0, &sa[0][o0]);
    stage16(ga1, &sa[0][o1]);
    stage16(gb0, &sb[0][o0]);
    stage16(gb1, &sb[0][o1]);
    __syncthreads();

    const int nt = K >> 5;
    int cur = 0;
    for (int t = 0; t < nt; ++t) {
        // issue next tile's staging first (overlaps with ds_read+MFMA below)
        if (t + 1 < nt) {
            const int k1 = (t + 1) << 5;
            stage16(ga0 + k1, &sa[cur ^ 1][o0]);
            stage16(ga1 + k1, &sa[cur ^ 1][o1]);
            stage16(gb0 + k1, &sb[cur ^ 1][o0]);
            stage16(gb1 + k1, &sb[cur ^ 1][o1]);
        }
        bf16x8 af[4], bfr[4];
        #pragma unroll
        for (int i = 0; i < 4; ++i) {
            af[i]  = *reinterpret_cast<const bf16x8*>(&sa[cur][(wr * 64 + i * 16 + fr) * 32 + kro]);
            bfr[i] = *reinterpret_cast<const bf16x8*>(&sb[cur][(wc * 64 + i * 16 + fr) * 32 + kro]);
        }
        #pragma unroll
        for (int mi = 0; mi < 4; ++mi)
            #pragma unroll
            for (int ni = 0; ni < 4; ++ni)
                acc[mi][ni] = __builtin_amdgcn_mfma_f32_16x16x32_bf16(af[mi], bfr[ni], acc[mi][ni], 0, 0, 0);
        __syncthreads();   // drains prefetch vmcnt + protects buf reuse
        cur ^= 1;
    }

    #pragma unroll
    for (int mi = 0; mi < 4; ++mi) {
        #pragma unroll
        for (int ni = 0; ni < 4; ++ni) {
            const int gc = n0 + wc * 64 + ni * 16 + fr;
            const float bv = (MODE != 0) ? bias[gc] : 0.f;
            #pragma unroll
            for (int r = 0; r < 4; ++r) {
                const int gr = m0 + wr * 64 + mi * 16 + (lane >> 4) * 4 + r;
                float v = acc[mi][ni][r] + bv;
                if (MODE == 1) v += resid[(size_t)gr * N + gc];
                if (MODE == 2) v = fmaxf(v, 0.f);
                if (MODE == 0 || MODE == 2) {
                    ((unsigned short*)outp)[(size_t)gr * N + gc] = f2bf(v);
                } else {
                    ((float*)outp)[(size_t)gr * N + gc] = v;
                }
            }
        }
    }
}

// ---------------------------------------------------------------- sparse attention v2.5
__global__ __launch_bounds__(256) void attn_kernel(
    const unsigned short* __restrict__ qkv, const int* __restrict__ rc,
    unsigned short* __restrict__ attnout)
{
    __shared__ unsigned short Kw[80 * 64];   // swizzled 16B chunks
    __shared__ unsigned short Vw[80 * 64];   // linear
    __shared__ float ewA[4][64];             // window weights (per wave)
    __shared__ float cwW[4][40];             // compacted B weights (per wave)
    __shared__ int   cwC[4][40];             // compacted B cols   (per wave)

    const int tid = threadIdx.x;
    const int wave = tid >> 6, lane = tid & 63;
    const int bid = blockIdx.x;
    const int tb = bid & 127;            // T/QB = 128
    const int h = (bid >> 7) & 7;
    const int b = bid >> 10;
    const int t0 = tb * QB;
    const int base = t0 - 63;

    const unsigned short* kb = qkv + (size_t)b * SEQT * 1536 + 512 + h * 64;
    const unsigned short* vb = qkv + (size_t)b * SEQT * 1536 + 1024 + h * 64;

    // stage window rows [base, t0+15] (79 rows): K swizzled, V linear
    for (int c = tid; c < 79 * 8; c += 256) {
        const int r = c >> 3, j = c & 7;
        const int col = base + r;
        u16x8 kv = {0, 0, 0, 0, 0, 0, 0, 0};
        u16x8 vv = {0, 0, 0, 0, 0, 0, 0, 0};
        if (col >= 0) {
            kv = *(const u16x8*)&kb[(size_t)col * 1536 + j * 8];
            vv = *(const u16x8*)&vb[(size_t)col * 1536 + j * 8];
        }
        *(u16x8*)&Kw[r * 64 + ((j ^ (r & 7)) * 8)] = kv;
        *(u16x8*)&Vw[r * 64 + j * 8] = vv;
    }
    __syncthreads();

    for (int u = 0; u < 4; ++u) {
        const int Q = wave * 4 + u;
        const int t = t0 + Q;
        const int m = b * SEQT + t;

        // Q row (wave-uniform, L1-broadcast) in regs
        u16x8 qreg[8];
        #pragma unroll
        for (int j = 0; j < 8; ++j)
            qreg[j] = *(const u16x8*)&qkv[(size_t)m * 1536 + h * 64 + j * 8];

        // ---- window score (slot A): LDS K row, branchless compute + select
        const int row = Q + lane;            // 0..78, always safe
        const int colA = base + row;
        float sA;
        {
            float s = 0.f;
            #pragma unroll
            for (int j = 0; j < 8; ++j) {
                const u16x8 kc = *(const u16x8*)&Kw[row * 64 + ((j ^ (row & 7)) * 8)];
                #pragma unroll
                for (int e = 0; e < 8; ++e)
                    s += bf2f(kc[e]) * bf2f(qreg[j][e]);
            }
            sA = (colA >= NGLOB) ? s * 0.125f : -1e30f;
        }

        // ---- B candidates: lanes 0..15 global, 16..31 random; shfl dedup
        int colB = 0;
        bool vB = false;
        if (lane < NGLOB) {
            colB = lane;
            vB = (lane <= t);
        } else if (lane < 32) {
            colB = rc[((size_t)h * SEQT + t) * NRAND + (lane - 16)];
            vB = (colB >= NGLOB) && (colB <= t - WIN);
        }
        #pragma unroll
        for (int j = 0; j < 15; ++j) {
            const int cj = __shfl(colB, 16 + j);
            if (lane >= 16 && lane < 32 && (lane - 16) > j && cj == colB) vB = false;
        }

        // ---- per-lane scattered QK-B dot (16 global + <=16 random lanes, parallel)
        float sB = -1e30f;
        if (vB) {
            float s = 0.f;
            const unsigned short* kr = &kb[(size_t)colB * 1536];
            #pragma unroll
            for (int j = 0; j < 8; ++j) {
                const u16x8 kc = *(const u16x8*)&kr[j * 8];
                #pragma unroll
                for (int e = 0; e < 8; ++e)
                    s += bf2f(kc[e]) * bf2f(qreg[j][e]);
            }
            sB = s * 0.125f;
        }

        // ---- softmax across the wave
        float mx = fmaxf(sA, sB);
        #pragma unroll
        for (int off = 32; off > 0; off >>= 1) mx = fmaxf(mx, __shfl_xor(mx, off));
        const float e0 = (colA >= NGLOB) ? __expf(sA - mx) : 0.f;
        const float e1 = vB ? __expf(sB - mx) : 0.f;
        float sum = e0 + e1;
        #pragma unroll
        for (int off = 32; off > 0; off >>= 1) sum += __shfl_xor(sum, off);
        const float inv = 1.f / sum;

        // ---- stash weights (per-wave LDS; same-wave write->read, no barrier)
        ewA[wave][lane] = e0;
        const unsigned long long bm = __ballot(vB);
        const int nB = __popcll(bm);
        const int pos = __popcll(bm & ((1ull << lane) - 1ull));
        if (vB) { cwC[wave][pos] = colB; cwW[wave][pos] = e1; }
        if (lane >= 32 && lane < 36) {       // pad to multiple of 4 (nB <= 32)
            const int p = nB + (lane - 32);
            cwC[wave][p] = 0; cwW[wave][p] = 0.f;
        }

        // ---- PV window: LDS V, branch-free
        float acc = 0.f;
        #pragma unroll 8
        for (int s = 0; s < 64; ++s)
            acc += ewA[wave][s] * bf2f(Vw[(Q + s) * 64 + lane]);

        // ---- PV-B: compacted, 4-wide branch-free (4 loads in flight)
        const int nB4 = (nB + 3) & ~3;
        for (int i = 0; i < nB4; i += 4) {
            const float w0 = cwW[wave][i + 0], w1 = cwW[wave][i + 1];
            const float w2 = cwW[wave][i + 2], w3 = cwW[wave][i + 3];
            const int   c0 = cwC[wave][i + 0], c1 = cwC[wave][i + 1];
            const int   c2 = cwC[wave][i + 2], c3 = cwC[wave][i + 3];
            const float x0 = bf2f(vb[(size_t)c0 * 1536 + lane]);
            const float x1 = bf2f(vb[(size_t)c1 * 1536 + lane]);
            const float x2 = bf2f(vb[(size_t)c2 * 1536 + lane]);
            const float x3 = bf2f(vb[(size_t)c3 * 1536 + lane]);
            acc += w0 * x0 + w1 * x1 + w2 * x2 + w3 * x3;
        }

        attnout[(size_t)m * CEMB + h * 64 + lane] = f2bf(acc * inv);
    }
}

// ---------------------------------------------------------------- host
extern "C" void kernel_launch(void* const* d_in, const int* in_sizes, int n_in,
                              void* d_out, int out_size, void* d_ws, size_t ws_size,
                              hipStream_t stream)
{
    const float* tok_emb = (const float*)d_in[0];
    const float* pos_emb = (const float*)d_in[1];
    const float* Wq    = (const float*)d_in[2];
    const float* Wk    = (const float*)d_in[3];
    const float* Wv    = (const float*)d_in[4];
    const float* Wproj = (const float*)d_in[5];
    const float* bproj = (const float*)d_in[6];
    const float* ln1g  = (const float*)d_in[7];
    const float* ln1b  = (const float*)d_in[8];
    const float* ln2g  = (const float*)d_in[9];
    const float* ln2b  = (const float*)d_in[10];
    const float* W1    = (const float*)d_in[11];
    const float* b1    = (const float*)d_in[12];
    const float* W2    = (const float*)d_in[13];
    const float* b2    = (const float*)d_in[14];
    const float* lnfg  = (const float*)d_in[15];
    const float* lnfb  = (const float*)d_in[16];
    const float* Wout  = (const float*)d_in[17];
    const float* bout  = (const float*)d_in[18];
    const int*   toks  = (const int*)d_in[19];
    const int*   rcols = (const int*)d_in[20];
    (void)in_sizes; (void)n_in; (void)out_size; (void)ws_size;

    char* ws = (char*)d_ws;
    size_t off = 0;
    auto ALLOC = [&](size_t bytes) -> void* {
        void* p = ws + off;
        off += (bytes + 255) & ~(size_t)255;
        return p;
    };
    float*          x      = (float*)ALLOC((size_t)MROWS * CEMB * 4);
    unsigned short* xnbf   = (unsigned short*)ALLOC((size_t)MROWS * CEMB * 2);
    unsigned short* qkv    = (unsigned short*)ALLOC((size_t)MROWS * 1536 * 2);
    unsigned short* attnbf = (unsigned short*)ALLOC((size_t)MROWS * CEMB * 2);
    unsigned short* hbf    = (unsigned short*)ALLOC((size_t)MROWS * 2048 * 2);
    unsigned short* wqkvT  = (unsigned short*)ALLOC((size_t)NLAYER * 1536 * 512 * 2);
    unsigned short* wprojT = (unsigned short*)ALLOC((size_t)NLAYER * 512 * 512 * 2);
    unsigned short* w1T    = (unsigned short*)ALLOC((size_t)NLAYER * 2048 * 512 * 2);
    unsigned short* w2T    = (unsigned short*)ALLOC((size_t)NLAYER * 512 * 2048 * 2);
    unsigned short* woutT  = (unsigned short*)ALLOC((size_t)VOCAB_N * 512 * 2);

    transpose_all_kernel<<<7072, 256, 0, stream>>>(
        Wq, Wk, Wv, Wproj, W1, W2, Wout, wqkvT, wprojT, w1T, w2T, woutT);

    embed_kernel<<<2048, 256, 0, stream>>>(tok_emb, pos_emb, toks, x);

    for (int l = 0; l < NLAYER; ++l) {
        ln_kernel<<<1024, 256, 0, stream>>>(x, ln1g + l * CEMB, ln1b + l * CEMB, xnbf);
        gemm_kernel<0, false><<<dim3(12, 32), 256, 0, stream>>>(
            xnbf, wqkvT + (size_t)l * 1536 * 512, nullptr, nullptr, qkv, MROWS, 1536, 512);
        attn_kernel<<<2048, 256, 0, stream>>>(qkv, rcols + (size_t)l * NHEAD * SEQT * NRAND, attnbf);
        gemm_kernel<1, false><<<dim3(4, 32), 256, 0, stream>>>(
            attnbf, wprojT + (size_t)l * 512 * 512, bproj + l * CEMB, x, x, MROWS, 512, 512);
        ln_kernel<<<1024, 256, 0, stream>>>(x, ln2g + l * CEMB, ln2b + l * CEMB, xnbf);
        gemm_kernel<2, false><<<dim3(16, 32), 256, 0, stream>>>(
            xnbf, w1T + (size_t)l * 2048 * 512, b1 + l * 2048, nullptr, hbf, MROWS, 2048, 512);
        gemm_kernel<1, false><<<dim3(4, 32), 256, 0, stream>>>(
            hbf, w2T + (size_t)l * 512 * 2048, b2 + l * CEMB, x, x, MROWS, 512, 2048);
    }
    ln_kernel<<<1024, 256, 0, stream>>>(x, lnfg, lnfb, xnbf);
    gemm_kernel<3, true><<<dim3(250, 32), 256, 0, stream>>>(
        xnbf, woutT, bout, nullptr, d_out, MROWS, VOCAB_N, 512);
}

// Round 7
// 1037.037 us; speedup vs baseline: 1.3630x; 1.0315x over previous
//
#include <hip/hip_runtime.h>
#include <hip/hip_bf16.h>

#define NLAYER 4
#define NHEAD 8
#define CEMB 512
#define HS 64
#define VOCAB_N 32000
#define SEQT 2048
#define BATCH_N 2
#define MROWS (BATCH_N * SEQT)   /* 4096 */
#define WIN 64
#define NGLOB 16
#define NRAND 16
#define QB 16                    /* queries per attention block */

typedef __attribute__((ext_vector_type(8))) __bf16 bf16x8;
typedef __attribute__((ext_vector_type(4))) float f32x4;
typedef __attribute__((ext_vector_type(8))) unsigned short u16x8;

__device__ __forceinline__ unsigned short f2bf(float f) {
    unsigned u = __float_as_uint(f);
    u += 0x7fffu + ((u >> 16) & 1u);      // RNE
    return (unsigned short)(u >> 16);
}
__device__ __forceinline__ float bf2f(unsigned short v) {
    return __uint_as_float((unsigned)v << 16);
}

// async global->LDS, 16B per lane, dest = wave-uniform base + lane*16
__device__ __forceinline__ void stage16(const unsigned short* g, unsigned short* l) {
    __builtin_amdgcn_global_load_lds(
        (const __attribute__((address_space(1))) void*)g,
        (__attribute__((address_space(3))) void*)l, 16, 0, 0);
}

// ---------------------------------------------------------------- unified weight transpose
__global__ __launch_bounds__(256) void transpose_all_kernel(
    const float* __restrict__ Wq, const float* __restrict__ Wk,
    const float* __restrict__ Wv, const float* __restrict__ Wproj,
    const float* __restrict__ W1, const float* __restrict__ W2,
    const float* __restrict__ Wout,
    unsigned short* __restrict__ wqkvT, unsigned short* __restrict__ wprojT,
    unsigned short* __restrict__ w1T, unsigned short* __restrict__ w2T,
    unsigned short* __restrict__ woutT)
{
    __shared__ float tle[64][65];
    const int bid = blockIdx.x;
    const float* src; unsigned short* dst; int Ks, Ns, k0, n0;
    if (bid < 768) {                       // Wq/Wk/Wv: [C=512,HS=64] -> [64,512] per (l,sel,h)
        const int tile = bid & 7, rest = bid >> 3;       // rest < 96
        const int l = rest / 24, r2 = rest % 24;
        const int sel = r2 >> 3, h = r2 & 7;
        const float* W = (sel == 0) ? Wq : (sel == 1) ? Wk : Wv;
        src = W + (size_t)(l * 8 + h) * 512 * 64;
        dst = wqkvT + ((size_t)l * 1536 + sel * 512 + h * 64) * 512;
        Ks = 512; Ns = 64; k0 = tile * 64; n0 = 0;
    } else if (bid < 1024) {               // Wproj [512,512] x4
        const int idx = bid - 768, l = idx >> 6, t6 = idx & 63;
        src = Wproj + (size_t)l * 512 * 512;
        dst = wprojT + (size_t)l * 512 * 512;
        Ks = 512; Ns = 512; k0 = (t6 >> 3) * 64; n0 = (t6 & 7) * 64;
    } else if (bid < 2048) {               // W1 [512,2048] x4
        const int idx = bid - 1024, l = idx >> 8, t8 = idx & 255;
        src = W1 + (size_t)l * 512 * 2048;
        dst = w1T + (size_t)l * 2048 * 512;
        Ks = 512; Ns = 2048; k0 = (t8 >> 5) * 64; n0 = (t8 & 31) * 64;
    } else if (bid < 3072) {               // W2 [2048,512] x4
        const int idx = bid - 2048, l = idx >> 8, t8 = idx & 255;
        src = W2 + (size_t)l * 2048 * 512;
        dst = w2T + (size_t)l * 512 * 2048;
        Ks = 2048; Ns = 512; k0 = (t8 >> 3) * 64; n0 = (t8 & 7) * 64;
    } else {                               // Wout [512,32000]
        const int idx = bid - 3072;        // 0..3999
        src = Wout; dst = woutT;
        Ks = 512; Ns = 32000; k0 = (idx / 500) * 64; n0 = (idx % 500) * 64;
    }
    const int tid = threadIdx.x;
    #pragma unroll
    for (int i = 0; i < 16; ++i) {
        const int idx = tid + i * 256;
        const int r = idx >> 6, c = idx & 63;
        tle[r][c] = src[(size_t)(k0 + r) * Ns + n0 + c];
    }
    __syncthreads();
    #pragma unroll
    for (int i = 0; i < 16; ++i) {
        const int idx = tid + i * 256;
        const int c = idx >> 6, r = idx & 63;
        dst[(size_t)(n0 + c) * Ks + k0 + r] = f2bf(tle[r][c]);
    }
}

// ---------------------------------------------------------------- embedding
__global__ __launch_bounds__(256) void embed_kernel(
    const float* __restrict__ tok_emb, const float* __restrict__ pos_emb,
    const int* __restrict__ toks, float* __restrict__ x)
{
    int i = blockIdx.x * 256 + threadIdx.x;
    int m = i >> 7;
    int c = (i & 127) << 2;
    int tok = toks[m];
    const float4 a = *(const float4*)&tok_emb[(size_t)tok * CEMB + c];
    const float4 p = *(const float4*)&pos_emb[(size_t)(m & (SEQT - 1)) * CEMB + c];
    float4 o;
    o.x = a.x + p.x; o.y = a.y + p.y; o.z = a.z + p.z; o.w = a.w + p.w;
    *(float4*)&x[(size_t)m * CEMB + c] = o;
}

// ---------------------------------------------------------------- layernorm
__global__ __launch_bounds__(256) void ln_kernel(
    const float* __restrict__ x, const float* __restrict__ g,
    const float* __restrict__ b, unsigned short* __restrict__ out)
{
    const int wave = threadIdx.x >> 6, lane = threadIdx.x & 63;
    const int m = blockIdx.x * 4 + wave;
    const float* row = x + (size_t)m * CEMB;
    const float4 v0 = *(const float4*)&row[lane * 8];
    const float4 v1 = *(const float4*)&row[lane * 8 + 4];
    float s  = v0.x + v0.y + v0.z + v0.w + v1.x + v1.y + v1.z + v1.w;
    float s2 = v0.x*v0.x + v0.y*v0.y + v0.z*v0.z + v0.w*v0.w
             + v1.x*v1.x + v1.y*v1.y + v1.z*v1.z + v1.w*v1.w;
    #pragma unroll
    for (int off = 32; off > 0; off >>= 1) {
        s  += __shfl_xor(s, off);
        s2 += __shfl_xor(s2, off);
    }
    const float mu  = s * (1.f / CEMB);
    const float var = s2 * (1.f / CEMB) - mu * mu;
    const float rs  = rsqrtf(var + 1e-5f);
    const float vals[8] = {v0.x, v0.y, v0.z, v0.w, v1.x, v1.y, v1.z, v1.w};
    u16x8 o;
    #pragma unroll
    for (int j = 0; j < 8; ++j)
        o[j] = f2bf((vals[j] - mu) * rs * g[lane * 8 + j] + b[lane * 8 + j]);
    *(u16x8*)&out[(size_t)m * CEMB + lane * 8] = o;
}

// ---------------------------------------------------------------- MFMA GEMM, 2-phase pipelined
// Tile = 128 x (NF*32). 4 waves: wr=wave>>1 (2 M-pos), wc=wave&1 (2 N-pos),
// each wave 64 x (NF*16), acc[4][NF]. Double-buffered LDS, STAGE(t+1) before
// compute(t), one barrier per K-step.
// SWZ 0: none. SWZ 2: column-major XCD-chunked (logits; gridDim.y must be 32,
//        total blocks % 8 == 0) -> 32 row-blocks sharing a B-panel run
//        consecutively on one XCD (B-panel L2-resident).
// MODE 0: bf16 out, no bias | 1: f32 out +bias +resid | 2: bf16 out +bias relu
// MODE 3: f32 out +bias (logits)
template<int MODE, int NF, int SWZ>
__global__ __launch_bounds__(256) void gemm_kernel(
    const unsigned short* __restrict__ A, const unsigned short* __restrict__ Bt,
    const float* __restrict__ bias, const float* resid, void* outp,
    int M, int N, int K)
{
    __shared__ unsigned short sa[2][128 * 32];
    __shared__ unsigned short sb[2][NF * 32 * 32];
    const int tid = threadIdx.x;
    const int lane = tid & 63;
    const int wave = tid >> 6;
    const int wr = wave >> 1, wc = wave & 1;

    int bx = blockIdx.x, by = blockIdx.y;
    if (SWZ == 2) {
        const int flat = by * gridDim.x + bx;       // dispatch order (x fastest)
        const int q = (gridDim.x * gridDim.y) >> 3;
        const int nl = (flat & 7) * q + (flat >> 3);
        by = nl & 31;          // M-block (32 of them)
        bx = nl >> 5;          // N-block
    }
    const int m0 = by * 128;
    const int n0 = bx * (NF * 32);

    // A staging: 512 chunks, 2 per lane; wave w owns segments {2w, 2w+1}
    const int c0a = (wave * 2) * 64 + lane;
    const int c1a = (wave * 2 + 1) * 64 + lane;
    const int r0 = c0a >> 2, kk0 = (c0a & 3) * 8;
    const int r1 = c1a >> 2, kk1 = (c1a & 3) * 8;
    const unsigned short* ga0 = A + (size_t)(m0 + r0) * K + kk0;
    const unsigned short* ga1 = A + (size_t)(m0 + r1) * K + kk1;
    const int o0 = (wave * 2) * 512;
    const int o1 = (wave * 2 + 1) * 512;
    // B staging: NF*128 chunks; NF=4: 2/lane, NF=2: 1/lane
    const int cb0 = (NF == 4) ? c0a : wave * 64 + lane;
    const int cb1 = c1a;                           // used only when NF==4
    const int rb0 = cb0 >> 2, kb0 = (cb0 & 3) * 8;
    const int rb1 = cb1 >> 2, kb1 = (cb1 & 3) * 8;
    const unsigned short* gb0 = Bt + (size_t)(n0 + rb0) * K + kb0;
    const unsigned short* gb1 = Bt + (size_t)(n0 + rb1) * K + kb1;
    const int ob0 = (NF == 4) ? o0 : wave * 512;
    const int ob1 = o1;

    f32x4 acc[4][NF] = {};
    const int kro = (lane >> 4) * 8;
    const int fr = lane & 15;

    // prologue: stage tile 0 into buffer 0
    stage16(ga0, &sa[0][o0]);
    stage16(ga1, &sa[0][o1]);
    stage16(gb0, &sb[0][ob0]);
    if (NF == 4) stage16(gb1, &sb[0][ob1]);
    __syncthreads();

    const int nt = K >> 5;
    int cur = 0;
    for (int t = 0; t < nt; ++t) {
        if (t + 1 < nt) {
            const int k1 = (t + 1) << 5;
            stage16(ga0 + k1, &sa[cur ^ 1][o0]);
            stage16(ga1 + k1, &sa[cur ^ 1][o1]);
            stage16(gb0 + k1, &sb[cur ^ 1][ob0]);
            if (NF == 4) stage16(gb1 + k1, &sb[cur ^ 1][ob1]);
        }
        bf16x8 af[4], bfr[NF];
        #pragma unroll
        for (int i = 0; i < 4; ++i)
            af[i] = *reinterpret_cast<const bf16x8*>(&sa[cur][(wr * 64 + i * 16 + fr) * 32 + kro]);
        #pragma unroll
        for (int i = 0; i < NF; ++i)
            bfr[i] = *reinterpret_cast<const bf16x8*>(&sb[cur][(wc * (NF * 16) + i * 16 + fr) * 32 + kro]);
        #pragma unroll
        for (int mi = 0; mi < 4; ++mi)
            #pragma unroll
            for (int ni = 0; ni < NF; ++ni)
                acc[mi][ni] = __builtin_amdgcn_mfma_f32_16x16x32_bf16(af[mi], bfr[ni], acc[mi][ni], 0, 0, 0);
        __syncthreads();   // drains prefetch vmcnt + protects buf reuse
        cur ^= 1;
    }

    #pragma unroll
    for (int mi = 0; mi < 4; ++mi) {
        #pragma unroll
        for (int ni = 0; ni < NF; ++ni) {
            const int gc = n0 + wc * (NF * 16) + ni * 16 + fr;
            const float bv = (MODE != 0) ? bias[gc] : 0.f;
            #pragma unroll
            for (int r = 0; r < 4; ++r) {
                const int gr = m0 + wr * 64 + mi * 16 + (lane >> 4) * 4 + r;
                float v = acc[mi][ni][r] + bv;
                if (MODE == 1) v += resid[(size_t)gr * N + gc];
                if (MODE == 2) v = fmaxf(v, 0.f);
                if (MODE == 0 || MODE == 2) {
                    ((unsigned short*)outp)[(size_t)gr * N + gc] = f2bf(v);
                } else {
                    ((float*)outp)[(size_t)gr * N + gc] = v;
                }
            }
        }
    }
}

// ---------------------------------------------------------------- sparse attention v2.5
__global__ __launch_bounds__(256) void attn_kernel(
    const unsigned short* __restrict__ qkv, const int* __restrict__ rc,
    unsigned short* __restrict__ attnout)
{
    __shared__ unsigned short Kw[80 * 64];   // swizzled 16B chunks
    __shared__ unsigned short Vw[80 * 64];   // linear
    __shared__ float ewA[4][64];             // window weights (per wave)
    __shared__ float cwW[4][40];             // compacted B weights (per wave)
    __shared__ int   cwC[4][40];             // compacted B cols   (per wave)

    const int tid = threadIdx.x;
    const int wave = tid >> 6, lane = tid & 63;
    const int bid = blockIdx.x;
    const int tb = bid & 127;            // T/QB = 128
    const int h = (bid >> 7) & 7;
    const int b = bid >> 10;
    const int t0 = tb * QB;
    const int base = t0 - 63;

    const unsigned short* kb = qkv + (size_t)b * SEQT * 1536 + 512 + h * 64;
    const unsigned short* vb = qkv + (size_t)b * SEQT * 1536 + 1024 + h * 64;

    // stage window rows [base, t0+15] (79 rows): K swizzled, V linear
    for (int c = tid; c < 79 * 8; c += 256) {
        const int r = c >> 3, j = c & 7;
        const int col = base + r;
        u16x8 kv = {0, 0, 0, 0, 0, 0, 0, 0};
        u16x8 vv = {0, 0, 0, 0, 0, 0, 0, 0};
        if (col >= 0) {
            kv = *(const u16x8*)&kb[(size_t)col * 1536 + j * 8];
            vv = *(const u16x8*)&vb[(size_t)col * 1536 + j * 8];
        }
        *(u16x8*)&Kw[r * 64 + ((j ^ (r & 7)) * 8)] = kv;
        *(u16x8*)&Vw[r * 64 + j * 8] = vv;
    }
    __syncthreads();

    for (int u = 0; u < 4; ++u) {
        const int Q = wave * 4 + u;
        const int t = t0 + Q;
        const int m = b * SEQT + t;

        // Q row (wave-uniform, L1-broadcast) in regs
        u16x8 qreg[8];
        #pragma unroll
        for (int j = 0; j < 8; ++j)
            qreg[j] = *(const u16x8*)&qkv[(size_t)m * 1536 + h * 64 + j * 8];

        // ---- window score (slot A): LDS K row, branchless compute + select
        const int row = Q + lane;            // 0..78, always safe
        const int colA = base + row;
        float sA;
        {
            float s = 0.f;
            #pragma unroll
            for (int j = 0; j < 8; ++j) {
                const u16x8 kc = *(const u16x8*)&Kw[row * 64 + ((j ^ (row & 7)) * 8)];
                #pragma unroll
                for (int e = 0; e < 8; ++e)
                    s += bf2f(kc[e]) * bf2f(qreg[j][e]);
            }
            sA = (colA >= NGLOB) ? s * 0.125f : -1e30f;
        }

        // ---- B candidates: lanes 0..15 global, 16..31 random; shfl dedup
        int colB = 0;
        bool vB = false;
        if (lane < NGLOB) {
            colB = lane;
            vB = (lane <= t);
        } else if (lane < 32) {
            colB = rc[((size_t)h * SEQT + t) * NRAND + (lane - 16)];
            vB = (colB >= NGLOB) && (colB <= t - WIN);
        }
        #pragma unroll
        for (int j = 0; j < 15; ++j) {
            const int cj = __shfl(colB, 16 + j);
            if (lane >= 16 && lane < 32 && (lane - 16) > j && cj == colB) vB = false;
        }

        // ---- per-lane scattered QK-B dot (16 global + <=16 random lanes, parallel)
        float sB = -1e30f;
        if (vB) {
            float s = 0.f;
            const unsigned short* kr = &kb[(size_t)colB * 1536];
            #pragma unroll
            for (int j = 0; j < 8; ++j) {
                const u16x8 kc = *(const u16x8*)&kr[j * 8];
                #pragma unroll
                for (int e = 0; e < 8; ++e)
                    s += bf2f(kc[e]) * bf2f(qreg[j][e]);
            }
            sB = s * 0.125f;
        }

        // ---- softmax across the wave
        float mx = fmaxf(sA, sB);
        #pragma unroll
        for (int off = 32; off > 0; off >>= 1) mx = fmaxf(mx, __shfl_xor(mx, off));
        const float e0 = (colA >= NGLOB) ? __expf(sA - mx) : 0.f;
        const float e1 = vB ? __expf(sB - mx) : 0.f;
        float sum = e0 + e1;
        #pragma unroll
        for (int off = 32; off > 0; off >>= 1) sum += __shfl_xor(sum, off);
        const float inv = 1.f / sum;

        // ---- stash weights (per-wave LDS; same-wave write->read, no barrier)
        ewA[wave][lane] = e0;
        const unsigned long long bm = __ballot(vB);
        const int nB = __popcll(bm);
        const int pos = __popcll(bm & ((1ull << lane) - 1ull));
        if (vB) { cwC[wave][pos] = colB; cwW[wave][pos] = e1; }
        if (lane >= 32 && lane < 36) {       // pad to multiple of 4 (nB <= 32)
            const int p = nB + (lane - 32);
            cwC[wave][p] = 0; cwW[wave][p] = 0.f;
        }

        // ---- PV window: LDS V, branch-free
        float acc = 0.f;
        #pragma unroll 8
        for (int s = 0; s < 64; ++s)
            acc += ewA[wave][s] * bf2f(Vw[(Q + s) * 64 + lane]);

        // ---- PV-B: compacted, 4-wide branch-free (4 loads in flight)
        const int nB4 = (nB + 3) & ~3;
        for (int i = 0; i < nB4; i += 4) {
            const float w0 = cwW[wave][i + 0], w1 = cwW[wave][i + 1];
            const float w2 = cwW[wave][i + 2], w3 = cwW[wave][i + 3];
            const int   c0 = cwC[wave][i + 0], c1 = cwC[wave][i + 1];
            const int   c2 = cwC[wave][i + 2], c3 = cwC[wave][i + 3];
            const float x0 = bf2f(vb[(size_t)c0 * 1536 + lane]);
            const float x1 = bf2f(vb[(size_t)c1 * 1536 + lane]);
            const float x2 = bf2f(vb[(size_t)c2 * 1536 + lane]);
            const float x3 = bf2f(vb[(size_t)c3 * 1536 + lane]);
            acc += w0 * x0 + w1 * x1 + w2 * x2 + w3 * x3;
        }

        attnout[(size_t)m * CEMB + h * 64 + lane] = f2bf(acc * inv);
    }
}

// ---------------------------------------------------------------- host
extern "C" void kernel_launch(void* const* d_in, const int* in_sizes, int n_in,
                              void* d_out, int out_size, void* d_ws, size_t ws_size,
                              hipStream_t stream)
{
    const float* tok_emb = (const float*)d_in[0];
    const float* pos_emb = (const float*)d_in[1];
    const float* Wq    = (const float*)d_in[2];
    const float* Wk    = (const float*)d_in[3];
    const float* Wv    = (const float*)d_in[4];
    const float* Wproj = (const float*)d_in[5];
    const float* bproj = (const float*)d_in[6];
    const float* ln1g  = (const float*)d_in[7];
    const float* ln1b  = (const float*)d_in[8];
    const float* ln2g  = (const float*)d_in[9];
    const float* ln2b  = (const float*)d_in[10];
    const float* W1    = (const float*)d_in[11];
    const float* b1    = (const float*)d_in[12];
    const float* W2    = (const float*)d_in[13];
    const float* b2    = (const float*)d_in[14];
    const float* lnfg  = (const float*)d_in[15];
    const float* lnfb  = (const float*)d_in[16];
    const float* Wout  = (const float*)d_in[17];
    const float* bout  = (const float*)d_in[18];
    const int*   toks  = (const int*)d_in[19];
    const int*   rcols = (const int*)d_in[20];
    (void)in_sizes; (void)n_in; (void)out_size; (void)ws_size;

    char* ws = (char*)d_ws;
    size_t off = 0;
    auto ALLOC = [&](size_t bytes) -> void* {
        void* p = ws + off;
        off += (bytes + 255) & ~(size_t)255;
        return p;
    };
    float*          x      = (float*)ALLOC((size_t)MROWS * CEMB * 4);
    unsigned short* xnbf   = (unsigned short*)ALLOC((size_t)MROWS * CEMB * 2);
    unsigned short* qkv    = (unsigned short*)ALLOC((size_t)MROWS * 1536 * 2);
    unsigned short* attnbf = (unsigned short*)ALLOC((size_t)MROWS * CEMB * 2);
    unsigned short* hbf    = (unsigned short*)ALLOC((size_t)MROWS * 2048 * 2);
    unsigned short* wqkvT  = (unsigned short*)ALLOC((size_t)NLAYER * 1536 * 512 * 2);
    unsigned short* wprojT = (unsigned short*)ALLOC((size_t)NLAYER * 512 * 512 * 2);
    unsigned short* w1T    = (unsigned short*)ALLOC((size_t)NLAYER * 2048 * 512 * 2);
    unsigned short* w2T    = (unsigned short*)ALLOC((size_t)NLAYER * 512 * 2048 * 2);
    unsigned short* woutT  = (unsigned short*)ALLOC((size_t)VOCAB_N * 512 * 2);

    transpose_all_kernel<<<7072, 256, 0, stream>>>(
        Wq, Wk, Wv, Wproj, W1, W2, Wout, wqkvT, wprojT, w1T, w2T, woutT);

    embed_kernel<<<2048, 256, 0, stream>>>(tok_emb, pos_emb, toks, x);

    for (int l = 0; l < NLAYER; ++l) {
        ln_kernel<<<1024, 256, 0, stream>>>(x, ln1g + l * CEMB, ln1b + l * CEMB, xnbf);
        gemm_kernel<0, 2, 0><<<dim3(24, 32), 256, 0, stream>>>(
            xnbf, wqkvT + (size_t)l * 1536 * 512, nullptr, nullptr, qkv, MROWS, 1536, 512);
        attn_kernel<<<2048, 256, 0, stream>>>(qkv, rcols + (size_t)l * NHEAD * SEQT * NRAND, attnbf);
        gemm_kernel<1, 2, 0><<<dim3(8, 32), 256, 0, stream>>>(
            attnbf, wprojT + (size_t)l * 512 * 512, bproj + l * CEMB, x, x, MROWS, 512, 512);
        ln_kernel<<<1024, 256, 0, stream>>>(x, ln2g + l * CEMB, ln2b + l * CEMB, xnbf);
        gemm_kernel<2, 4, 0><<<dim3(16, 32), 256, 0, stream>>>(
            xnbf, w1T + (size_t)l * 2048 * 512, b1 + l * 2048, nullptr, hbf, MROWS, 2048, 512);
        gemm_kernel<1, 2, 0><<<dim3(8, 32), 256, 0, stream>>>(
            hbf, w2T + (size_t)l * 512 * 2048, b2 + l * CEMB, x, x, MROWS, 512, 2048);
    }
    ln_kernel<<<1024, 256, 0, stream>>>(x, lnfg, lnfb, xnbf);
    gemm_kernel<3, 4, 2><<<dim3(250, 32), 256, 0, stream>>>(
        xnbf, woutT, bout, nullptr, d_out, MROWS, VOCAB_N, 512);
}

// Round 8
// 1034.712 us; speedup vs baseline: 1.3660x; 1.0022x over previous
//
#include <hip/hip_runtime.h>
#include <hip/hip_bf16.h>

#define NLAYER 4
#define NHEAD 8
#define CEMB 512
#define HS 64
#define VOCAB_N 32000
#define SEQT 2048
#define BATCH_N 2
#define MROWS (BATCH_N * SEQT)   /* 4096 */
#define WIN 64
#define NGLOB 16
#define NRAND 16
#define QB 16                    /* queries per attention block */

typedef __attribute__((ext_vector_type(8))) __bf16 bf16x8;
typedef __attribute__((ext_vector_type(4))) float f32x4;
typedef __attribute__((ext_vector_type(8))) unsigned short u16x8;

__device__ __forceinline__ unsigned short f2bf(float f) {
    unsigned u = __float_as_uint(f);
    u += 0x7fffu + ((u >> 16) & 1u);      // RNE
    return (unsigned short)(u >> 16);
}
__device__ __forceinline__ float bf2f(unsigned short v) {
    return __uint_as_float((unsigned)v << 16);
}

// async global->LDS, 16B per lane, dest = wave-uniform base + lane*16
__device__ __forceinline__ void stage16(const unsigned short* g, unsigned short* l) {
    __builtin_amdgcn_global_load_lds(
        (const __attribute__((address_space(1))) void*)g,
        (__attribute__((address_space(3))) void*)l, 16, 0, 0);
}

// ---------------------------------------------------------------- unified weight transpose
__global__ __launch_bounds__(256) void transpose_all_kernel(
    const float* __restrict__ Wq, const float* __restrict__ Wk,
    const float* __restrict__ Wv, const float* __restrict__ Wproj,
    const float* __restrict__ W1, const float* __restrict__ W2,
    const float* __restrict__ Wout,
    unsigned short* __restrict__ wqkvT, unsigned short* __restrict__ wprojT,
    unsigned short* __restrict__ w1T, unsigned short* __restrict__ w2T,
    unsigned short* __restrict__ woutT)
{
    __shared__ float tle[64][65];
    const int bid = blockIdx.x;
    const float* src; unsigned short* dst; int Ks, Ns, k0, n0;
    if (bid < 768) {                       // Wq/Wk/Wv: [C=512,HS=64] -> [64,512] per (l,sel,h)
        const int tile = bid & 7, rest = bid >> 3;       // rest < 96
        const int l = rest / 24, r2 = rest % 24;
        const int sel = r2 >> 3, h = r2 & 7;
        const float* W = (sel == 0) ? Wq : (sel == 1) ? Wk : Wv;
        src = W + (size_t)(l * 8 + h) * 512 * 64;
        dst = wqkvT + ((size_t)l * 1536 + sel * 512 + h * 64) * 512;
        Ks = 512; Ns = 64; k0 = tile * 64; n0 = 0;
    } else if (bid < 1024) {               // Wproj [512,512] x4
        const int idx = bid - 768, l = idx >> 6, t6 = idx & 63;
        src = Wproj + (size_t)l * 512 * 512;
        dst = wprojT + (size_t)l * 512 * 512;
        Ks = 512; Ns = 512; k0 = (t6 >> 3) * 64; n0 = (t6 & 7) * 64;
    } else if (bid < 2048) {               // W1 [512,2048] x4
        const int idx = bid - 1024, l = idx >> 8, t8 = idx & 255;
        src = W1 + (size_t)l * 512 * 2048;
        dst = w1T + (size_t)l * 2048 * 512;
        Ks = 512; Ns = 2048; k0 = (t8 >> 5) * 64; n0 = (t8 & 31) * 64;
    } else if (bid < 3072) {               // W2 [2048,512] x4
        const int idx = bid - 2048, l = idx >> 8, t8 = idx & 255;
        src = W2 + (size_t)l * 2048 * 512;
        dst = w2T + (size_t)l * 512 * 2048;
        Ks = 2048; Ns = 512; k0 = (t8 >> 3) * 64; n0 = (t8 & 7) * 64;
    } else {                               // Wout [512,32000]
        const int idx = bid - 3072;        // 0..3999
        src = Wout; dst = woutT;
        Ks = 512; Ns = 32000; k0 = (idx / 500) * 64; n0 = (idx % 500) * 64;
    }
    const int tid = threadIdx.x;
    #pragma unroll
    for (int i = 0; i < 16; ++i) {
        const int idx = tid + i * 256;
        const int r = idx >> 6, c = idx & 63;
        tle[r][c] = src[(size_t)(k0 + r) * Ns + n0 + c];
    }
    __syncthreads();
    #pragma unroll
    for (int i = 0; i < 16; ++i) {
        const int idx = tid + i * 256;
        const int c = idx >> 6, r = idx & 63;
        dst[(size_t)(n0 + c) * Ks + k0 + r] = f2bf(tle[r][c]);
    }
}

// ---------------------------------------------------------------- embedding
__global__ __launch_bounds__(256) void embed_kernel(
    const float* __restrict__ tok_emb, const float* __restrict__ pos_emb,
    const int* __restrict__ toks, float* __restrict__ x)
{
    int i = blockIdx.x * 256 + threadIdx.x;
    int m = i >> 7;
    int c = (i & 127) << 2;
    int tok = toks[m];
    const float4 a = *(const float4*)&tok_emb[(size_t)tok * CEMB + c];
    const float4 p = *(const float4*)&pos_emb[(size_t)(m & (SEQT - 1)) * CEMB + c];
    float4 o;
    o.x = a.x + p.x; o.y = a.y + p.y; o.z = a.z + p.z; o.w = a.w + p.w;
    *(float4*)&x[(size_t)m * CEMB + c] = o;
}

// ---------------------------------------------------------------- layernorm
__global__ __launch_bounds__(256) void ln_kernel(
    const float* __restrict__ x, const float* __restrict__ g,
    const float* __restrict__ b, unsigned short* __restrict__ out)
{
    const int wave = threadIdx.x >> 6, lane = threadIdx.x & 63;
    const int m = blockIdx.x * 4 + wave;
    const float* row = x + (size_t)m * CEMB;
    const float4 v0 = *(const float4*)&row[lane * 8];
    const float4 v1 = *(const float4*)&row[lane * 8 + 4];
    float s  = v0.x + v0.y + v0.z + v0.w + v1.x + v1.y + v1.z + v1.w;
    float s2 = v0.x*v0.x + v0.y*v0.y + v0.z*v0.z + v0.w*v0.w
             + v1.x*v1.x + v1.y*v1.y + v1.z*v1.z + v1.w*v1.w;
    #pragma unroll
    for (int off = 32; off > 0; off >>= 1) {
        s  += __shfl_xor(s, off);
        s2 += __shfl_xor(s2, off);
    }
    const float mu  = s * (1.f / CEMB);
    const float var = s2 * (1.f / CEMB) - mu * mu;
    const float rs  = rsqrtf(var + 1e-5f);
    const float vals[8] = {v0.x, v0.y, v0.z, v0.w, v1.x, v1.y, v1.z, v1.w};
    u16x8 o;
    #pragma unroll
    for (int j = 0; j < 8; ++j)
        o[j] = f2bf((vals[j] - mu) * rs * g[lane * 8 + j] + b[lane * 8 + j]);
    *(u16x8*)&out[(size_t)m * CEMB + lane * 8] = o;
}

// ---------------------------------------------------------------- MFMA GEMM, triple-buffered + counted vmcnt
// Tile = 128 x (NF*32). 4 waves. 3 LDS buffers, prefetch depth 2; per K-step:
//   s_waitcnt vmcnt(S)   (own tile-t stages landed; t+1 stays in flight)
//   raw s_barrier        (no compiler vmcnt(0) drain!)
//   stage tile t+2 -> buf[(t+2)%3]   (safe: its old tile read before barrier)
//   ds_read + MFMA tile t
// S = stage instrs/thread/tile (NF=2: 3, NF=4: 4). Never vmcnt(0) mid-loop (T4).
// SWZ 2: column-major XCD-chunked (logits). MODE as before.
template<int MODE, int NF, int SWZ>
__global__ __launch_bounds__(256) void gemm_kernel(
    const unsigned short* __restrict__ A, const unsigned short* __restrict__ Bt,
    const float* __restrict__ bias, const float* resid, void* outp,
    int M, int N, int K)
{
    __shared__ unsigned short sa[3][128 * 32];
    __shared__ unsigned short sb[3][NF * 32 * 32];
    const int tid = threadIdx.x;
    const int lane = tid & 63;
    const int wave = tid >> 6;
    const int wr = wave >> 1, wc = wave & 1;

    int bx = blockIdx.x, by = blockIdx.y;
    if (SWZ == 2) {
        const int flat = by * gridDim.x + bx;       // dispatch order (x fastest)
        const int q = (gridDim.x * gridDim.y) >> 3;
        const int nl = (flat & 7) * q + (flat >> 3);
        by = nl & 31;          // M-block (32 of them)
        bx = nl >> 5;          // N-block
    }
    const int m0 = by * 128;
    const int n0 = bx * (NF * 32);

    // A staging: 512 chunks, 2 per lane; wave w owns segments {2w, 2w+1}
    const int c0a = (wave * 2) * 64 + lane;
    const int c1a = (wave * 2 + 1) * 64 + lane;
    const int r0 = c0a >> 2, kk0 = (c0a & 3) * 8;
    const int r1 = c1a >> 2, kk1 = (c1a & 3) * 8;
    const unsigned short* ga0 = A + (size_t)(m0 + r0) * K + kk0;
    const unsigned short* ga1 = A + (size_t)(m0 + r1) * K + kk1;
    const int o0 = (wave * 2) * 512;
    const int o1 = (wave * 2 + 1) * 512;
    // B staging: NF*128 chunks; NF=4: 2/lane, NF=2: 1/lane
    const int cb0 = (NF == 4) ? c0a : wave * 64 + lane;
    const int cb1 = c1a;                           // used only when NF==4
    const int rb0 = cb0 >> 2, kb0 = (cb0 & 3) * 8;
    const int rb1 = cb1 >> 2, kb1 = (cb1 & 3) * 8;
    const unsigned short* gb0 = Bt + (size_t)(n0 + rb0) * K + kb0;
    const unsigned short* gb1 = Bt + (size_t)(n0 + rb1) * K + kb1;
    const int ob0 = (NF == 4) ? o0 : wave * 512;
    const int ob1 = o1;

    f32x4 acc[4][NF] = {};
    const int kro = (lane >> 4) * 8;
    const int fr = lane & 15;

    auto STAGE = [&](int tile, int buf) {
        const int kk = tile << 5;
        stage16(ga0 + kk, &sa[buf][o0]);
        stage16(ga1 + kk, &sa[buf][o1]);
        stage16(gb0 + kk, &sb[buf][ob0]);
        if constexpr (NF == 4) stage16(gb1 + kk, &sb[buf][ob1]);
    };

    const int nt = K >> 5;
    // prologue: stage tiles 0 and 1
    STAGE(0, 0);
    STAGE(1, 1);

    int cur = 0;
    for (int t = 0; t < nt; ++t) {
        // wait: own tile-t stages landed; keep tile t+1 in flight (counted, not 0)
        if (t + 1 < nt) {
            if constexpr (NF == 2) asm volatile("s_waitcnt vmcnt(3)" ::: "memory");
            else                   asm volatile("s_waitcnt vmcnt(4)" ::: "memory");
        } else {
            asm volatile("s_waitcnt vmcnt(0)" ::: "memory");
        }
        __builtin_amdgcn_s_barrier();        // raw: no implicit vmcnt(0) drain
        __builtin_amdgcn_sched_barrier(0);   // pin: nothing crosses the barrier

        if (t + 2 < nt) {
            int b2 = cur + 2; if (b2 >= 3) b2 -= 3;
            STAGE(t + 2, b2);
        }

        bf16x8 af[4], bfr[NF];
        #pragma unroll
        for (int i = 0; i < 4; ++i)
            af[i] = *reinterpret_cast<const bf16x8*>(&sa[cur][(wr * 64 + i * 16 + fr) * 32 + kro]);
        #pragma unroll
        for (int i = 0; i < NF; ++i)
            bfr[i] = *reinterpret_cast<const bf16x8*>(&sb[cur][(wc * (NF * 16) + i * 16 + fr) * 32 + kro]);
        #pragma unroll
        for (int mi = 0; mi < 4; ++mi)
            #pragma unroll
            for (int ni = 0; ni < NF; ++ni)
                acc[mi][ni] = __builtin_amdgcn_mfma_f32_16x16x32_bf16(af[mi], bfr[ni], acc[mi][ni], 0, 0, 0);

        cur = (cur == 2) ? 0 : cur + 1;
    }

    #pragma unroll
    for (int mi = 0; mi < 4; ++mi) {
        #pragma unroll
        for (int ni = 0; ni < NF; ++ni) {
            const int gc = n0 + wc * (NF * 16) + ni * 16 + fr;
            const float bv = (MODE != 0) ? bias[gc] : 0.f;
            #pragma unroll
            for (int r = 0; r < 4; ++r) {
                const int gr = m0 + wr * 64 + mi * 16 + (lane >> 4) * 4 + r;
                float v = acc[mi][ni][r] + bv;
                if (MODE == 1) v += resid[(size_t)gr * N + gc];
                if (MODE == 2) v = fmaxf(v, 0.f);
                if (MODE == 0 || MODE == 2) {
                    ((unsigned short*)outp)[(size_t)gr * N + gc] = f2bf(v);
                } else {
                    ((float*)outp)[(size_t)gr * N + gc] = v;
                }
            }
        }
    }
}

// ---------------------------------------------------------------- sparse attention v2.5
__global__ __launch_bounds__(256) void attn_kernel(
    const unsigned short* __restrict__ qkv, const int* __restrict__ rc,
    unsigned short* __restrict__ attnout)
{
    __shared__ unsigned short Kw[80 * 64];   // swizzled 16B chunks
    __shared__ unsigned short Vw[80 * 64];   // linear
    __shared__ float ewA[4][64];             // window weights (per wave)
    __shared__ float cwW[4][40];             // compacted B weights (per wave)
    __shared__ int   cwC[4][40];             // compacted B cols   (per wave)

    const int tid = threadIdx.x;
    const int wave = tid >> 6, lane = tid & 63;
    const int bid = blockIdx.x;
    const int tb = bid & 127;            // T/QB = 128
    const int h = (bid >> 7) & 7;
    const int b = bid >> 10;
    const int t0 = tb * QB;
    const int base = t0 - 63;

    const unsigned short* kb = qkv + (size_t)b * SEQT * 1536 + 512 + h * 64;
    const unsigned short* vb = qkv + (size_t)b * SEQT * 1536 + 1024 + h * 64;

    // stage window rows [base, t0+15] (79 rows): K swizzled, V linear
    for (int c = tid; c < 79 * 8; c += 256) {
        const int r = c >> 3, j = c & 7;
        const int col = base + r;
        u16x8 kv = {0, 0, 0, 0, 0, 0, 0, 0};
        u16x8 vv = {0, 0, 0, 0, 0, 0, 0, 0};
        if (col >= 0) {
            kv = *(const u16x8*)&kb[(size_t)col * 1536 + j * 8];
            vv = *(const u16x8*)&vb[(size_t)col * 1536 + j * 8];
        }
        *(u16x8*)&Kw[r * 64 + ((j ^ (r & 7)) * 8)] = kv;
        *(u16x8*)&Vw[r * 64 + j * 8] = vv;
    }
    __syncthreads();

    for (int u = 0; u < 4; ++u) {
        const int Q = wave * 4 + u;
        const int t = t0 + Q;
        const int m = b * SEQT + t;

        // Q row (wave-uniform, L1-broadcast) in regs
        u16x8 qreg[8];
        #pragma unroll
        for (int j = 0; j < 8; ++j)
            qreg[j] = *(const u16x8*)&qkv[(size_t)m * 1536 + h * 64 + j * 8];

        // ---- window score (slot A): LDS K row, branchless compute + select
        const int row = Q + lane;            // 0..78, always safe
        const int colA = base + row;
        float sA;
        {
            float s = 0.f;
            #pragma unroll
            for (int j = 0; j < 8; ++j) {
                const u16x8 kc = *(const u16x8*)&Kw[row * 64 + ((j ^ (row & 7)) * 8)];
                #pragma unroll
                for (int e = 0; e < 8; ++e)
                    s += bf2f(kc[e]) * bf2f(qreg[j][e]);
            }
            sA = (colA >= NGLOB) ? s * 0.125f : -1e30f;
        }

        // ---- B candidates: lanes 0..15 global, 16..31 random; shfl dedup
        int colB = 0;
        bool vB = false;
        if (lane < NGLOB) {
            colB = lane;
            vB = (lane <= t);
        } else if (lane < 32) {
            colB = rc[((size_t)h * SEQT + t) * NRAND + (lane - 16)];
            vB = (colB >= NGLOB) && (colB <= t - WIN);
        }
        #pragma unroll
        for (int j = 0; j < 15; ++j) {
            const int cj = __shfl(colB, 16 + j);
            if (lane >= 16 && lane < 32 && (lane - 16) > j && cj == colB) vB = false;
        }

        // ---- per-lane scattered QK-B dot (16 global + <=16 random lanes, parallel)
        float sB = -1e30f;
        if (vB) {
            float s = 0.f;
            const unsigned short* kr = &kb[(size_t)colB * 1536];
            #pragma unroll
            for (int j = 0; j < 8; ++j) {
                const u16x8 kc = *(const u16x8*)&kr[j * 8];
                #pragma unroll
                for (int e = 0; e < 8; ++e)
                    s += bf2f(kc[e]) * bf2f(qreg[j][e]);
            }
            sB = s * 0.125f;
        }

        // ---- softmax across the wave
        float mx = fmaxf(sA, sB);
        #pragma unroll
        for (int off = 32; off > 0; off >>= 1) mx = fmaxf(mx, __shfl_xor(mx, off));
        const float e0 = (colA >= NGLOB) ? __expf(sA - mx) : 0.f;
        const float e1 = vB ? __expf(sB - mx) : 0.f;
        float sum = e0 + e1;
        #pragma unroll
        for (int off = 32; off > 0; off >>= 1) sum += __shfl_xor(sum, off);
        const float inv = 1.f / sum;

        // ---- stash weights (per-wave LDS; same-wave write->read, no barrier)
        ewA[wave][lane] = e0;
        const unsigned long long bm = __ballot(vB);
        const int nB = __popcll(bm);
        const int pos = __popcll(bm & ((1ull << lane) - 1ull));
        if (vB) { cwC[wave][pos] = colB; cwW[wave][pos] = e1; }
        if (lane >= 32 && lane < 36) {       // pad to multiple of 4 (nB <= 32)
            const int p = nB + (lane - 32);
            cwC[wave][p] = 0; cwW[wave][p] = 0.f;
        }

        // ---- PV window: LDS V, branch-free
        float acc = 0.f;
        #pragma unroll 8
        for (int s = 0; s < 64; ++s)
            acc += ewA[wave][s] * bf2f(Vw[(Q + s) * 64 + lane]);

        // ---- PV-B: compacted, 4-wide branch-free (4 loads in flight)
        const int nB4 = (nB + 3) & ~3;
        for (int i = 0; i < nB4; i += 4) {
            const float w0 = cwW[wave][i + 0], w1 = cwW[wave][i + 1];
            const float w2 = cwW[wave][i + 2], w3 = cwW[wave][i + 3];
            const int   c0 = cwC[wave][i + 0], c1 = cwC[wave][i + 1];
            const int   c2 = cwC[wave][i + 2], c3 = cwC[wave][i + 3];
            const float x0 = bf2f(vb[(size_t)c0 * 1536 + lane]);
            const float x1 = bf2f(vb[(size_t)c1 * 1536 + lane]);
            const float x2 = bf2f(vb[(size_t)c2 * 1536 + lane]);
            const float x3 = bf2f(vb[(size_t)c3 * 1536 + lane]);
            acc += w0 * x0 + w1 * x1 + w2 * x2 + w3 * x3;
        }

        attnout[(size_t)m * CEMB + h * 64 + lane] = f2bf(acc * inv);
    }
}

// ---------------------------------------------------------------- host
extern "C" void kernel_launch(void* const* d_in, const int* in_sizes, int n_in,
                              void* d_out, int out_size, void* d_ws, size_t ws_size,
                              hipStream_t stream)
{
    const float* tok_emb = (const float*)d_in[0];
    const float* pos_emb = (const float*)d_in[1];
    const float* Wq    = (const float*)d_in[2];
    const float* Wk    = (const float*)d_in[3];
    const float* Wv    = (const float*)d_in[4];
    const float* Wproj = (const float*)d_in[5];
    const float* bproj = (const float*)d_in[6];
    const float* ln1g  = (const float*)d_in[7];
    const float* ln1b  = (const float*)d_in[8];
    const float* ln2g  = (const float*)d_in[9];
    const float* ln2b  = (const float*)d_in[10];
    const float* W1    = (const float*)d_in[11];
    const float* b1    = (const float*)d_in[12];
    const float* W2    = (const float*)d_in[13];
    const float* b2    = (const float*)d_in[14];
    const float* lnfg  = (const float*)d_in[15];
    const float* lnfb  = (const float*)d_in[16];
    const float* Wout  = (const float*)d_in[17];
    const float* bout  = (const float*)d_in[18];
    const int*   toks  = (const int*)d_in[19];
    const int*   rcols = (const int*)d_in[20];
    (void)in_sizes; (void)n_in; (void)out_size; (void)ws_size;

    char* ws = (char*)d_ws;
    size_t off = 0;
    auto ALLOC = [&](size_t bytes) -> void* {
        void* p = ws + off;
        off += (bytes + 255) & ~(size_t)255;
        return p;
    };
    float*          x      = (float*)ALLOC((size_t)MROWS * CEMB * 4);
    unsigned short* xnbf   = (unsigned short*)ALLOC((size_t)MROWS * CEMB * 2);
    unsigned short* qkv    = (unsigned short*)ALLOC((size_t)MROWS * 1536 * 2);
    unsigned short* attnbf = (unsigned short*)ALLOC((size_t)MROWS * CEMB * 2);
    unsigned short* hbf    = (unsigned short*)ALLOC((size_t)MROWS * 2048 * 2);
    unsigned short* wqkvT  = (unsigned short*)ALLOC((size_t)NLAYER * 1536 * 512 * 2);
    unsigned short* wprojT = (unsigned short*)ALLOC((size_t)NLAYER * 512 * 512 * 2);
    unsigned short* w1T    = (unsigned short*)ALLOC((size_t)NLAYER * 2048 * 512 * 2);
    unsigned short* w2T    = (unsigned short*)ALLOC((size_t)NLAYER * 512 * 2048 * 2);
    unsigned short* woutT  = (unsigned short*)ALLOC((size_t)VOCAB_N * 512 * 2);

    transpose_all_kernel<<<7072, 256, 0, stream>>>(
        Wq, Wk, Wv, Wproj, W1, W2, Wout, wqkvT, wprojT, w1T, w2T, woutT);

    embed_kernel<<<2048, 256, 0, stream>>>(tok_emb, pos_emb, toks, x);

    for (int l = 0; l < NLAYER; ++l) {
        ln_kernel<<<1024, 256, 0, stream>>>(x, ln1g + l * CEMB, ln1b + l * CEMB, xnbf);
        gemm_kernel<0, 2, 0><<<dim3(24, 32), 256, 0, stream>>>(
            xnbf, wqkvT + (size_t)l * 1536 * 512, nullptr, nullptr, qkv, MROWS, 1536, 512);
        attn_kernel<<<2048, 256, 0, stream>>>(qkv, rcols + (size_t)l * NHEAD * SEQT * NRAND, attnbf);
        gemm_kernel<1, 2, 0><<<dim3(8, 32), 256, 0, stream>>>(
            attnbf, wprojT + (size_t)l * 512 * 512, bproj + l * CEMB, x, x, MROWS, 512, 512);
        ln_kernel<<<1024, 256, 0, stream>>>(x, ln2g + l * CEMB, ln2b + l * CEMB, xnbf);
        gemm_kernel<2, 4, 0><<<dim3(16, 32), 256, 0, stream>>>(
            xnbf, w1T + (size_t)l * 2048 * 512, b1 + l * 2048, nullptr, hbf, MROWS, 2048, 512);
        gemm_kernel<1, 2, 0><<<dim3(8, 32), 256, 0, stream>>>(
            hbf, w2T + (size_t)l * 512 * 2048, b2 + l * CEMB, x, x, MROWS, 512, 2048);
    }
    ln_kernel<<<1024, 256, 0, stream>>>(x, lnfg, lnfb, xnbf);
    gemm_kernel<3, 4, 2><<<dim3(250, 32), 256, 0, stream>>>(
        xnbf, woutT, bout, nullptr, d_out, MROWS, VOCAB_N, 512);
}